// Round 3
// baseline (256.867 us; speedup 1.0000x reference)
//
#include <hip/hip_runtime.h>
#include <math.h>

#define B_ 2048
#define S_ 16
#define D_ 768
#define H1_ 256
#define H2_ 128
#define P_ 126

static constexpr float EPS = 1e-6f;
static constexpr float BN_EPS = 1e-5f;
static constexpr float L_PCSL = 50.0f;
static constexpr float L_DANN = 0.5f;

// ---------------- K1: f[b,d] = mean over s of features[b,s,d] ----------------
// 2048 blocks x 192 threads, float4 over D=768.
__global__ __launch_bounds__(192) void k_mean(const float* __restrict__ feat,
                                              float* __restrict__ f) {
    int b = blockIdx.x;
    int t = threadIdx.x;  // 0..191
    const float4* src = (const float4*)(feat + (size_t)b * S_ * D_);
    float4 acc = make_float4(0.f, 0.f, 0.f, 0.f);
#pragma unroll
    for (int s = 0; s < S_; ++s) {
        float4 v = src[s * (D_ / 4) + t];
        acc.x += v.x; acc.y += v.y; acc.z += v.z; acc.w += v.w;
    }
    const float inv = 1.0f / (float)S_;
    acc.x *= inv; acc.y *= inv; acc.z *= inv; acc.w *= inv;
    ((float4*)(f + (size_t)b * D_))[t] = acc;
}

// ---------------- K2: per-patient centroid, sq, count (deterministic scan) ----
// 126 blocks x 192 threads.
__global__ __launch_bounds__(192) void k_centroid(const float* __restrict__ f,
                                                  const int* __restrict__ pid,
                                                  float* __restrict__ cent,
                                                  float* __restrict__ sq,
                                                  float* __restrict__ counts) {
    __shared__ int sid[B_];
    __shared__ float wred[3];
    int p = blockIdx.x;
    int t = threadIdx.x;
    for (int i = t; i < B_; i += blockDim.x) sid[i] = pid[i];
    __syncthreads();
    float4 acc = make_float4(0.f, 0.f, 0.f, 0.f);
    int cnt = 0;
    for (int b = 0; b < B_; ++b) {
        if (sid[b] == p) {
            ++cnt;
            float4 v = ((const float4*)(f + (size_t)b * D_))[t];
            acc.x += v.x; acc.y += v.y; acc.z += v.z; acc.w += v.w;
        }
    }
    float invc = 1.0f / (float)(cnt > 0 ? cnt : 1);
    acc.x *= invc; acc.y *= invc; acc.z *= invc; acc.w *= invc;
    ((float4*)(cent + (size_t)p * D_))[t] = acc;
    float ss = acc.x * acc.x + acc.y * acc.y + acc.z * acc.z + acc.w * acc.w;
    for (int off = 32; off; off >>= 1) ss += __shfl_down(ss, off, 64);
    if ((t & 63) == 0) wred[t >> 6] = ss;
    __syncthreads();
    if (t == 0) {
        sq[p] = wred[0] + wred[1] + wred[2];
        counts[p] = (float)cnt;
    }
}

// ---------------- K3: between + mapped-id table (single block) ---------------
// between = n_present * sum(sq) - ||sum_p centroid_p||^2  (absent centroids are 0)
__global__ __launch_bounds__(256) void k_between(const float* __restrict__ cent,
                                                 const float* __restrict__ sq,
                                                 const float* __restrict__ counts,
                                                 float* __restrict__ scal,
                                                 int* __restrict__ mapped) {
    int t = threadIdx.x;
    float acc = 0.f;
    for (int d = t; d < D_; d += 256) {
        float cs = 0.f;
        for (int p = 0; p < P_; ++p) cs += cent[(size_t)p * D_ + d];
        acc += cs * cs;
    }
    for (int off = 32; off; off >>= 1) acc += __shfl_down(acc, off, 64);
    __shared__ float wred[4];
    if ((t & 63) == 0) wred[t >> 6] = acc;
    __syncthreads();
    if (t == 0) {
        float B2 = wred[0] + wred[1] + wred[2] + wred[3];
        float ssq = 0.f;
        int run = 0;
        for (int p = 0; p < P_; ++p) {
            bool pres = counts[p] > 0.f;
            mapped[p] = pres ? run : -1;
            if (pres) { run++; ssq += sq[p]; }
        }
        scal[1] = (float)run * ssq - B2;  // between
    }
}

// ---------------- K4: within = sum((f - cent[pid])^2) ------------------------
__global__ __launch_bounds__(256) void k_within(const float* __restrict__ f,
                                                const int* __restrict__ pid,
                                                const float* __restrict__ cent,
                                                float* __restrict__ scal) {
    const int total = B_ * D_ / 4;
    int idx = blockIdx.x * blockDim.x + threadIdx.x;
    float accs = 0.f;
    for (int i = idx; i < total; i += gridDim.x * blockDim.x) {
        int b = i / (D_ / 4);
        int dd = i % (D_ / 4);
        float4 fv = ((const float4*)f)[i];
        float4 cv = ((const float4*)(cent + (size_t)pid[b] * D_))[dd];
        float dx = fv.x - cv.x, dy = fv.y - cv.y, dz = fv.z - cv.z, dw = fv.w - cv.w;
        accs += dx * dx + dy * dy + dz * dz + dw * dw;
    }
    for (int off = 32; off; off >>= 1) accs += __shfl_down(accs, off, 64);
    __shared__ float wred[4];
    if ((threadIdx.x & 63) == 0) wred[threadIdx.x >> 6] = accs;
    __syncthreads();
    if (threadIdx.x == 0) atomicAdd(&scal[0], wred[0] + wred[1] + wred[2] + wred[3]);
}

// ---------------- K5/K6: fp32 tiled GEMM + bias + BN(eval) + ReLU ------------
// C[M,N] = A[M,K] @ W[K,N]; out = relu((C + bias) * (gamma/sqrt(1+BN_EPS)) + beta)
// 64x64 tile, BK=16, 256 threads, 4x4 per thread.
template <int KDIM>
__global__ __launch_bounds__(256) void k_gemm_bn_relu(const float* __restrict__ A,
                                                      const float* __restrict__ W,
                                                      const float* __restrict__ bias,
                                                      const float* __restrict__ gamma,
                                                      const float* __restrict__ beta,
                                                      float* __restrict__ out, int N) {
    constexpr int BK = 16;
    __shared__ float As[BK][64 + 4];  // As[k][m]
    __shared__ float Bs[BK][64 + 4];  // Bs[k][n]
    int tid = threadIdx.x;
    int tx = tid & 15, ty = tid >> 4;
    int bm = blockIdx.x * 64, bn = blockIdx.y * 64;
    float c[4][4] = {};
    int lrow = tid >> 2;        // m in tile, 0..63
    int lcol = (tid & 3) * 4;   // k in tile {0,4,8,12}
    int brow = tid >> 4;        // k in tile for B, 0..15
    int bcol = (tid & 15) * 4;  // n in tile

    for (int k0 = 0; k0 < KDIM; k0 += BK) {
        float4 av = *(const float4*)(A + (size_t)(bm + lrow) * KDIM + k0 + lcol);
        float4 bv = *(const float4*)(W + (size_t)(k0 + brow) * N + bn + bcol);
        __syncthreads();
        As[lcol + 0][lrow] = av.x;
        As[lcol + 1][lrow] = av.y;
        As[lcol + 2][lrow] = av.z;
        As[lcol + 3][lrow] = av.w;
        *(float4*)&Bs[brow][bcol] = bv;
        __syncthreads();
#pragma unroll
        for (int kk = 0; kk < BK; ++kk) {
            float4 a4 = *(const float4*)&As[kk][ty * 4];
            float4 b4 = *(const float4*)&Bs[kk][tx * 4];
            float a_[4] = {a4.x, a4.y, a4.z, a4.w};
            float b_[4] = {b4.x, b4.y, b4.z, b4.w};
#pragma unroll
            for (int i = 0; i < 4; ++i)
#pragma unroll
                for (int j = 0; j < 4; ++j) c[i][j] += a_[i] * b_[j];
        }
    }

    const float inv_bn = rsqrtf(1.0f + BN_EPS);
    int col0 = bn + tx * 4;
    float sc[4], bb[4], bt[4];
#pragma unroll
    for (int j = 0; j < 4; ++j) {
        sc[j] = gamma[col0 + j] * inv_bn;
        bb[j] = bias[col0 + j];
        bt[j] = beta[col0 + j];
    }
#pragma unroll
    for (int i = 0; i < 4; ++i) {
        int row = bm + ty * 4 + i;
        float4 o;
        o.x = fmaxf((c[i][0] + bb[0]) * sc[0] + bt[0], 0.f);
        o.y = fmaxf((c[i][1] + bb[1]) * sc[1] + bt[1], 0.f);
        o.z = fmaxf((c[i][2] + bb[2]) * sc[2] + bt[2], 0.f);
        o.w = fmaxf((c[i][3] + bb[3]) * sc[3] + bt[3], 0.f);
        *(float4*)(out + (size_t)row * N + col0) = o;
    }
}

// ---------------- K7: logits + log-softmax + CE gather -----------------------
// W3 [128][126] staged in LDS; 8 rows per block; 128 threads (thread j = class j).
__global__ __launch_bounds__(128) void k_dann(const float* __restrict__ h2,
                                              const float* __restrict__ W3,
                                              const float* __restrict__ b3,
                                              const int* __restrict__ pid,
                                              const int* __restrict__ mapped,
                                              float* __restrict__ scal) {
    __shared__ float Ws[H2_][P_];  // 64512 B
    __shared__ float hrow[H2_];
    __shared__ float wmax[2], wsum[2], wfin[2];
    int t = threadIdx.x;
    for (int i = t; i < H2_ * P_; i += 128) Ws[i / P_][i % P_] = W3[i];
    int r0 = blockIdx.x * 8;
    float partial = 0.f;
    for (int r = 0; r < 8; ++r) {
        int b = r0 + r;
        __syncthreads();  // protect hrow/Ws (first iter) + wmax/wsum reuse
        hrow[t] = h2[(size_t)b * H2_ + t];
        __syncthreads();
        float logit = -INFINITY;
        if (t < P_) {
            float acc = b3[t];
#pragma unroll 8
            for (int k = 0; k < H2_; ++k) acc += hrow[k] * Ws[k][t];
            logit = acc;
        }
        float m = logit;
        for (int off = 32; off; off >>= 1) m = fmaxf(m, __shfl_down(m, off, 64));
        if ((t & 63) == 0) wmax[t >> 6] = m;
        __syncthreads();
        float M = fmaxf(wmax[0], wmax[1]);
        float e = (t < P_) ? __expf(logit - M) : 0.f;
        float se = e;
        for (int off = 32; off; off >>= 1) se += __shfl_down(se, off, 64);
        if ((t & 63) == 0) wsum[t >> 6] = se;
        __syncthreads();
        float SE = wsum[0] + wsum[1];
        int mb = mapped[pid[b]];
        if (t == mb) partial += (M + __logf(SE) - logit);
    }
    float s = partial;
    for (int off = 32; off; off >>= 1) s += __shfl_down(s, off, 64);
    if ((t & 63) == 0) wfin[t >> 6] = s;
    __syncthreads();
    if (t == 0) atomicAdd(&scal[2], wfin[0] + wfin[1]);
}

// ---------------- K8: combine --------------------------------------------------
__global__ void k_final(const float* __restrict__ scal, float* __restrict__ out) {
    float within = scal[0];
    float between = scal[1];
    float dann = scal[2];
    out[0] = L_PCSL * (within / (between + EPS)) + L_DANN * (dann / (float)B_);
}

extern "C" void kernel_launch(void* const* d_in, const int* in_sizes, int n_in,
                              void* d_out, int out_size, void* d_ws, size_t ws_size,
                              hipStream_t stream) {
    const float* feat = (const float*)d_in[0];
    const int* pid = (const int*)d_in[1];
    const float* W1 = (const float*)d_in[2];
    const float* b1 = (const float*)d_in[3];
    const float* g1 = (const float*)d_in[4];
    const float* be1 = (const float*)d_in[5];
    const float* W2 = (const float*)d_in[6];
    const float* b2 = (const float*)d_in[7];
    const float* g2 = (const float*)d_in[8];
    const float* be2 = (const float*)d_in[9];
    const float* W3 = (const float*)d_in[10];
    const float* b3 = (const float*)d_in[11];
    float* out = (float*)d_out;

    // Workspace layout (16B aligned chunks)
    char* w = (char*)d_ws;
    float* f = (float*)w;                              // B*D
    float* cent = f + (size_t)B_ * D_;                 // P*D
    float* h1 = cent + (size_t)P_ * D_;                // B*H1
    float* h2 = h1 + (size_t)B_ * H1_;                 // B*H2
    float* sq = h2 + (size_t)B_ * H2_;                 // 128 (P rounded)
    float* counts = sq + 128;                          // 128
    float* scal = counts + 128;                        // 16 scalars
    int* mapped = (int*)(scal + 16);                   // P ints

    // zero the atomic accumulators (scal[0]=within, [1]=between, [2]=dann)
    hipMemsetAsync(scal, 0, 16 * sizeof(float), stream);

    k_mean<<<B_, 192, 0, stream>>>(feat, f);
    k_centroid<<<P_, 192, 0, stream>>>(f, pid, cent, sq, counts);
    k_between<<<1, 256, 0, stream>>>(cent, sq, counts, scal, mapped);
    k_within<<<512, 256, 0, stream>>>(f, pid, cent, scal);
    k_gemm_bn_relu<D_><<<dim3(B_ / 64, H1_ / 64), 256, 0, stream>>>(f, W1, b1, g1, be1, h1, H1_);
    k_gemm_bn_relu<H1_><<<dim3(B_ / 64, H2_ / 64), 256, 0, stream>>>(h1, W2, b2, g2, be2, h2, H2_);
    k_dann<<<B_ / 8, 128, 0, stream>>>(h2, W3, b3, pid, mapped, scal);
    k_final<<<1, 1, 0, stream>>>(scal, out);
}

// Round 4
// 255.370 us; speedup vs baseline: 1.0059x; 1.0059x over previous
//
#include <hip/hip_runtime.h>
#include <math.h>

#define B_ 2048
#define S_ 16
#define D_ 768
#define H1_ 256
#define H2_ 128
#define P_ 126

static constexpr float EPS = 1e-6f;
static constexpr float BN_EPS = 1e-5f;
static constexpr float L_PCSL = 50.0f;
static constexpr float L_DANN = 0.5f;

// ---------------- K1: f[b,d] = mean over s of features[b,s,d] ----------------
// 2048 blocks x 192 threads, float4 over D=768.
__global__ __launch_bounds__(192) void k_mean(const float* __restrict__ feat,
                                              float* __restrict__ f) {
    int b = blockIdx.x;
    int t = threadIdx.x;  // 0..191
    const float4* src = (const float4*)(feat + (size_t)b * S_ * D_);
    float4 acc = make_float4(0.f, 0.f, 0.f, 0.f);
#pragma unroll
    for (int s = 0; s < S_; ++s) {
        float4 v = src[s * (D_ / 4) + t];
        acc.x += v.x; acc.y += v.y; acc.z += v.z; acc.w += v.w;
    }
    const float inv = 1.0f / (float)S_;
    acc.x *= inv; acc.y *= inv; acc.z *= inv; acc.w *= inv;
    ((float4*)(f + (size_t)b * D_))[t] = acc;
}

// ---------------- K2: per-patient centroid, sq, count (deterministic scan) ----
// 126 blocks x 192 threads.
__global__ __launch_bounds__(192) void k_centroid(const float* __restrict__ f,
                                                  const int* __restrict__ pid,
                                                  float* __restrict__ cent,
                                                  float* __restrict__ sq,
                                                  float* __restrict__ counts) {
    __shared__ int sid[B_];
    __shared__ float wred[3];
    int p = blockIdx.x;
    int t = threadIdx.x;
    for (int i = t; i < B_; i += blockDim.x) sid[i] = pid[i];
    __syncthreads();
    float4 acc = make_float4(0.f, 0.f, 0.f, 0.f);
    int cnt = 0;
    for (int b = 0; b < B_; ++b) {
        if (sid[b] == p) {
            ++cnt;
            float4 v = ((const float4*)(f + (size_t)b * D_))[t];
            acc.x += v.x; acc.y += v.y; acc.z += v.z; acc.w += v.w;
        }
    }
    float invc = 1.0f / (float)(cnt > 0 ? cnt : 1);
    acc.x *= invc; acc.y *= invc; acc.z *= invc; acc.w *= invc;
    ((float4*)(cent + (size_t)p * D_))[t] = acc;
    float ss = acc.x * acc.x + acc.y * acc.y + acc.z * acc.z + acc.w * acc.w;
    for (int off = 32; off; off >>= 1) ss += __shfl_down(ss, off, 64);
    if ((t & 63) == 0) wred[t >> 6] = ss;
    __syncthreads();
    if (t == 0) {
        sq[p] = wred[0] + wred[1] + wred[2];
        counts[p] = (float)cnt;
    }
}

// ---------------- K3: between + mapped-id table (single block) ---------------
// between = n_present * sum(sq) - ||sum_p centroid_p||^2  (absent centroids are 0)
__global__ __launch_bounds__(256) void k_between(const float* __restrict__ cent,
                                                 const float* __restrict__ sq,
                                                 const float* __restrict__ counts,
                                                 float* __restrict__ scal,
                                                 int* __restrict__ mapped) {
    int t = threadIdx.x;
    float acc = 0.f;
    for (int d = t; d < D_; d += 256) {
        float cs = 0.f;
        for (int p = 0; p < P_; ++p) cs += cent[(size_t)p * D_ + d];
        acc += cs * cs;
    }
    for (int off = 32; off; off >>= 1) acc += __shfl_down(acc, off, 64);
    __shared__ float wred[4];
    if ((t & 63) == 0) wred[t >> 6] = acc;
    __syncthreads();
    if (t == 0) {
        float B2 = wred[0] + wred[1] + wred[2] + wred[3];
        float ssq = 0.f;
        int run = 0;
        for (int p = 0; p < P_; ++p) {
            bool pres = counts[p] > 0.f;
            mapped[p] = pres ? run : -1;
            if (pres) { run++; ssq += sq[p]; }
        }
        scal[1] = (float)run * ssq - B2;  // between
    }
}

// ---------------- K4: within = sum((f - cent[pid])^2) ------------------------
__global__ __launch_bounds__(256) void k_within(const float* __restrict__ f,
                                                const int* __restrict__ pid,
                                                const float* __restrict__ cent,
                                                float* __restrict__ scal) {
    const int total = B_ * D_ / 4;
    int idx = blockIdx.x * blockDim.x + threadIdx.x;
    float accs = 0.f;
    for (int i = idx; i < total; i += gridDim.x * blockDim.x) {
        int b = i / (D_ / 4);
        int dd = i % (D_ / 4);
        float4 fv = ((const float4*)f)[i];
        float4 cv = ((const float4*)(cent + (size_t)pid[b] * D_))[dd];
        float dx = fv.x - cv.x, dy = fv.y - cv.y, dz = fv.z - cv.z, dw = fv.w - cv.w;
        accs += dx * dx + dy * dy + dz * dz + dw * dw;
    }
    for (int off = 32; off; off >>= 1) accs += __shfl_down(accs, off, 64);
    __shared__ float wred[4];
    if ((threadIdx.x & 63) == 0) wred[threadIdx.x >> 6] = accs;
    __syncthreads();
    if (threadIdx.x == 0) atomicAdd(&scal[0], wred[0] + wred[1] + wred[2] + wred[3]);
}

// ---------------- K5/K6: fp32 tiled GEMM + bias + BN(eval) + ReLU ------------
// C[M,N] = A[M,K] @ W[K,N]; out = relu((C + bias) * (gamma/sqrt(1+BN_EPS)) + beta)
// 64x64 tile, BK=16, 256 threads, 4x4 per thread.
template <int KDIM>
__global__ __launch_bounds__(256) void k_gemm_bn_relu(const float* __restrict__ A,
                                                      const float* __restrict__ W,
                                                      const float* __restrict__ bias,
                                                      const float* __restrict__ gamma,
                                                      const float* __restrict__ beta,
                                                      float* __restrict__ out, int N) {
    constexpr int BK = 16;
    __shared__ float As[BK][64 + 4];  // As[k][m]
    __shared__ float Bs[BK][64 + 4];  // Bs[k][n]
    int tid = threadIdx.x;
    int tx = tid & 15, ty = tid >> 4;
    int bm = blockIdx.x * 64, bn = blockIdx.y * 64;
    float c[4][4] = {};
    int lrow = tid >> 2;        // m in tile, 0..63
    int lcol = (tid & 3) * 4;   // k in tile {0,4,8,12}
    int brow = tid >> 4;        // k in tile for B, 0..15
    int bcol = (tid & 15) * 4;  // n in tile

    for (int k0 = 0; k0 < KDIM; k0 += BK) {
        float4 av = *(const float4*)(A + (size_t)(bm + lrow) * KDIM + k0 + lcol);
        float4 bv = *(const float4*)(W + (size_t)(k0 + brow) * N + bn + bcol);
        __syncthreads();
        As[lcol + 0][lrow] = av.x;
        As[lcol + 1][lrow] = av.y;
        As[lcol + 2][lrow] = av.z;
        As[lcol + 3][lrow] = av.w;
        *(float4*)&Bs[brow][bcol] = bv;
        __syncthreads();
#pragma unroll
        for (int kk = 0; kk < BK; ++kk) {
            float4 a4 = *(const float4*)&As[kk][ty * 4];
            float4 b4 = *(const float4*)&Bs[kk][tx * 4];
            float a_[4] = {a4.x, a4.y, a4.z, a4.w};
            float b_[4] = {b4.x, b4.y, b4.z, b4.w};
#pragma unroll
            for (int i = 0; i < 4; ++i)
#pragma unroll
                for (int j = 0; j < 4; ++j) c[i][j] += a_[i] * b_[j];
        }
    }

    const float inv_bn = rsqrtf(1.0f + BN_EPS);
    int col0 = bn + tx * 4;
    float sc[4], bb[4], bt[4];
#pragma unroll
    for (int j = 0; j < 4; ++j) {
        sc[j] = gamma[col0 + j] * inv_bn;
        bb[j] = bias[col0 + j];
        bt[j] = beta[col0 + j];
    }
#pragma unroll
    for (int i = 0; i < 4; ++i) {
        int row = bm + ty * 4 + i;
        float4 o;
        o.x = fmaxf((c[i][0] + bb[0]) * sc[0] + bt[0], 0.f);
        o.y = fmaxf((c[i][1] + bb[1]) * sc[1] + bt[1], 0.f);
        o.z = fmaxf((c[i][2] + bb[2]) * sc[2] + bt[2], 0.f);
        o.w = fmaxf((c[i][3] + bb[3]) * sc[3] + bt[3], 0.f);
        *(float4*)(out + (size_t)row * N + col0) = o;
    }
}

// ---------------- K7: logits + log-softmax + CE gather -----------------------
// W3 [128][126] staged in LDS; 8 rows per block; 128 threads (thread j = class j).
__global__ __launch_bounds__(128) void k_dann(const float* __restrict__ h2,
                                              const float* __restrict__ W3,
                                              const float* __restrict__ b3,
                                              const int* __restrict__ pid,
                                              const int* __restrict__ mapped,
                                              float* __restrict__ scal) {
    __shared__ float Ws[H2_][P_];  // 64512 B
    __shared__ float hrow[H2_];
    __shared__ float wmax[2], wsum[2], wfin[2];
    int t = threadIdx.x;
    for (int i = t; i < H2_ * P_; i += 128) Ws[i / P_][i % P_] = W3[i];
    int r0 = blockIdx.x * 8;
    float partial = 0.f;
    for (int r = 0; r < 8; ++r) {
        int b = r0 + r;
        __syncthreads();  // protect hrow/Ws (first iter) + wmax/wsum reuse
        hrow[t] = h2[(size_t)b * H2_ + t];
        __syncthreads();
        float logit = -INFINITY;
        if (t < P_) {
            float acc = b3[t];
#pragma unroll 8
            for (int k = 0; k < H2_; ++k) acc += hrow[k] * Ws[k][t];
            logit = acc;
        }
        float m = logit;
        for (int off = 32; off; off >>= 1) m = fmaxf(m, __shfl_down(m, off, 64));
        if ((t & 63) == 0) wmax[t >> 6] = m;
        __syncthreads();
        float M = fmaxf(wmax[0], wmax[1]);
        float e = (t < P_) ? __expf(logit - M) : 0.f;
        float se = e;
        for (int off = 32; off; off >>= 1) se += __shfl_down(se, off, 64);
        if ((t & 63) == 0) wsum[t >> 6] = se;
        __syncthreads();
        float SE = wsum[0] + wsum[1];
        int mb = mapped[pid[b]];
        if (t == mb) partial += (M + __logf(SE) - logit);
    }
    float s = partial;
    for (int off = 32; off; off >>= 1) s += __shfl_down(s, off, 64);
    if ((t & 63) == 0) wfin[t >> 6] = s;
    __syncthreads();
    if (t == 0) atomicAdd(&scal[2], wfin[0] + wfin[1]);
}

// ---------------- K8: combine --------------------------------------------------
__global__ void k_final(const float* __restrict__ scal, float* __restrict__ out) {
    float within = scal[0];
    float between = scal[1];
    float dann = scal[2];
    out[0] = L_PCSL * (within / (between + EPS)) + L_DANN * (dann / (float)B_);
}

extern "C" void kernel_launch(void* const* d_in, const int* in_sizes, int n_in,
                              void* d_out, int out_size, void* d_ws, size_t ws_size,
                              hipStream_t stream) {
    const float* feat = (const float*)d_in[0];
    const int* pid = (const int*)d_in[1];
    const float* W1 = (const float*)d_in[2];
    const float* b1 = (const float*)d_in[3];
    const float* g1 = (const float*)d_in[4];
    const float* be1 = (const float*)d_in[5];
    const float* W2 = (const float*)d_in[6];
    const float* b2 = (const float*)d_in[7];
    const float* g2 = (const float*)d_in[8];
    const float* be2 = (const float*)d_in[9];
    const float* W3 = (const float*)d_in[10];
    const float* b3 = (const float*)d_in[11];
    float* out = (float*)d_out;

    // Workspace layout (16B aligned chunks)
    char* w = (char*)d_ws;
    float* f = (float*)w;                              // B*D
    float* cent = f + (size_t)B_ * D_;                 // P*D
    float* h1 = cent + (size_t)P_ * D_;                // B*H1
    float* h2 = h1 + (size_t)B_ * H1_;                 // B*H2
    float* sq = h2 + (size_t)B_ * H2_;                 // 128 (P rounded)
    float* counts = sq + 128;                          // 128
    float* scal = counts + 128;                        // 16 scalars
    int* mapped = (int*)(scal + 16);                   // P ints

    // zero the atomic accumulators (scal[0]=within, [1]=between, [2]=dann)
    hipMemsetAsync(scal, 0, 16 * sizeof(float), stream);

    k_mean<<<B_, 192, 0, stream>>>(feat, f);
    k_centroid<<<P_, 192, 0, stream>>>(f, pid, cent, sq, counts);
    k_between<<<1, 256, 0, stream>>>(cent, sq, counts, scal, mapped);
    k_within<<<512, 256, 0, stream>>>(f, pid, cent, scal);
    k_gemm_bn_relu<D_><<<dim3(B_ / 64, H1_ / 64), 256, 0, stream>>>(f, W1, b1, g1, be1, h1, H1_);
    k_gemm_bn_relu<H1_><<<dim3(B_ / 64, H2_ / 64), 256, 0, stream>>>(h1, W2, b2, g2, be2, h2, H2_);
    k_dann<<<B_ / 8, 128, 0, stream>>>(h2, W3, b3, pid, mapped, scal);
    k_final<<<1, 1, 0, stream>>>(scal, out);
}

// Round 5
// 154.933 us; speedup vs baseline: 1.6579x; 1.6483x over previous
//
#include <hip/hip_runtime.h>
#include <math.h>

#define B_ 2048
#define S_ 16
#define D_ 768
#define H1_ 256
#define H2_ 128
#define P_ 126

static constexpr float EPS = 1e-6f;
static constexpr float BN_EPS = 1e-5f;
static constexpr float L_PCSL = 50.0f;
static constexpr float L_DANN = 0.5f;

// ---------------- K1: f[b,d] = mean over s of features[b,s,d] ----------------
// 2048 blocks x 192 threads, float4 over D=768.
__global__ __launch_bounds__(192) void k_mean(const float* __restrict__ feat,
                                              float* __restrict__ f) {
    int b = blockIdx.x;
    int t = threadIdx.x;  // 0..191
    const float4* src = (const float4*)(feat + (size_t)b * S_ * D_);
    float4 acc = make_float4(0.f, 0.f, 0.f, 0.f);
#pragma unroll
    for (int s = 0; s < S_; ++s) {
        float4 v = src[s * (D_ / 4) + t];
        acc.x += v.x; acc.y += v.y; acc.z += v.z; acc.w += v.w;
    }
    const float inv = 1.0f / (float)S_;
    acc.x *= inv; acc.y *= inv; acc.z *= inv; acc.w *= inv;
    ((float4*)(f + (size_t)b * D_))[t] = acc;
}

// ---------------- K2: per-patient centroid via ballot match-list --------------
// 126 blocks x 192 threads. Wave 0 builds the ascending list of sample indices
// belonging to patient p (32 ballot rounds), then all threads accumulate only
// the ~16 matching rows (4 loads in flight). Sum order = ascending b, identical
// to the previous serial scan.
__global__ __launch_bounds__(192) void k_centroid(const float* __restrict__ f,
                                                  const int* __restrict__ pid,
                                                  float* __restrict__ cent,
                                                  float* __restrict__ sq,
                                                  float* __restrict__ counts) {
    __shared__ int sid[B_];
    __shared__ int list[B_];
    __shared__ int s_cnt;
    __shared__ float wred[3];
    int p = blockIdx.x;
    int t = threadIdx.x;
    for (int i = t; i < B_; i += 192) sid[i] = pid[i];
    __syncthreads();

    if (t < 64) {
        int total = 0;
        unsigned long long lt_mask = (t == 63) ? 0x7fffffffffffffffull
                                               : ((1ull << t) - 1ull);
#pragma unroll 4
        for (int r = 0; r < B_ / 64; ++r) {
            int b = r * 64 + t;
            bool m = (sid[b] == p);
            unsigned long long mask = __ballot(m);
            if (m) {
                int pos = total + (int)__popcll(mask & lt_mask);
                list[pos] = b;
            }
            total += (int)__popcll(mask);
        }
        if (t == 0) s_cnt = total;
    }
    __syncthreads();

    int cnt = s_cnt;
    float4 acc = make_float4(0.f, 0.f, 0.f, 0.f);
    int i = 0;
    for (; i + 4 <= cnt; i += 4) {
        int b0 = list[i], b1 = list[i + 1], b2 = list[i + 2], b3 = list[i + 3];
        float4 v0 = ((const float4*)(f + (size_t)b0 * D_))[t];
        float4 v1 = ((const float4*)(f + (size_t)b1 * D_))[t];
        float4 v2 = ((const float4*)(f + (size_t)b2 * D_))[t];
        float4 v3 = ((const float4*)(f + (size_t)b3 * D_))[t];
        acc.x += v0.x + v1.x + v2.x + v3.x;
        acc.y += v0.y + v1.y + v2.y + v3.y;
        acc.z += v0.z + v1.z + v2.z + v3.z;
        acc.w += v0.w + v1.w + v2.w + v3.w;
    }
    for (; i < cnt; ++i) {
        float4 v = ((const float4*)(f + (size_t)list[i] * D_))[t];
        acc.x += v.x; acc.y += v.y; acc.z += v.z; acc.w += v.w;
    }

    float invc = 1.0f / (float)(cnt > 0 ? cnt : 1);
    acc.x *= invc; acc.y *= invc; acc.z *= invc; acc.w *= invc;
    ((float4*)(cent + (size_t)p * D_))[t] = acc;
    float ss = acc.x * acc.x + acc.y * acc.y + acc.z * acc.z + acc.w * acc.w;
    for (int off = 32; off; off >>= 1) ss += __shfl_down(ss, off, 64);
    if ((t & 63) == 0) wred[t >> 6] = ss;
    __syncthreads();
    if (t == 0) {
        sq[p] = wred[0] + wred[1] + wred[2];
        counts[p] = (float)cnt;
    }
}

// ---------------- K3: between + mapped-id table (single block) ---------------
// between = n_present * sum(sq) - ||sum_p centroid_p||^2  (absent centroids are 0)
__global__ __launch_bounds__(256) void k_between(const float* __restrict__ cent,
                                                 const float* __restrict__ sq,
                                                 const float* __restrict__ counts,
                                                 float* __restrict__ scal,
                                                 int* __restrict__ mapped) {
    int t = threadIdx.x;
    float acc = 0.f;
    for (int d = t; d < D_; d += 256) {
        float cs = 0.f;
        for (int p = 0; p < P_; ++p) cs += cent[(size_t)p * D_ + d];
        acc += cs * cs;
    }
    for (int off = 32; off; off >>= 1) acc += __shfl_down(acc, off, 64);
    __shared__ float wred[4];
    if ((t & 63) == 0) wred[t >> 6] = acc;
    __syncthreads();
    if (t == 0) {
        float B2 = wred[0] + wred[1] + wred[2] + wred[3];
        float ssq = 0.f;
        int run = 0;
        for (int p = 0; p < P_; ++p) {
            bool pres = counts[p] > 0.f;
            mapped[p] = pres ? run : -1;
            if (pres) { run++; ssq += sq[p]; }
        }
        scal[1] = (float)run * ssq - B2;  // between
    }
}

// ---------------- K4: within = sum((f - cent[pid])^2) ------------------------
__global__ __launch_bounds__(256) void k_within(const float* __restrict__ f,
                                                const int* __restrict__ pid,
                                                const float* __restrict__ cent,
                                                float* __restrict__ scal) {
    const int total = B_ * D_ / 4;
    int idx = blockIdx.x * blockDim.x + threadIdx.x;
    float accs = 0.f;
    for (int i = idx; i < total; i += gridDim.x * blockDim.x) {
        int b = i / (D_ / 4);
        int dd = i % (D_ / 4);
        float4 fv = ((const float4*)f)[i];
        float4 cv = ((const float4*)(cent + (size_t)pid[b] * D_))[dd];
        float dx = fv.x - cv.x, dy = fv.y - cv.y, dz = fv.z - cv.z, dw = fv.w - cv.w;
        accs += dx * dx + dy * dy + dz * dz + dw * dw;
    }
    for (int off = 32; off; off >>= 1) accs += __shfl_down(accs, off, 64);
    __shared__ float wred[4];
    if ((threadIdx.x & 63) == 0) wred[threadIdx.x >> 6] = accs;
    __syncthreads();
    if (threadIdx.x == 0) atomicAdd(&scal[0], wred[0] + wred[1] + wred[2] + wred[3]);
}

// ---------------- K5/K6: fp32 tiled GEMM + bias + BN(eval) + ReLU ------------
// C[M,N] = A[M,K] @ W[K,N]; out = relu((C + bias) * (gamma/sqrt(1+BN_EPS)) + beta)
// 64(M) x 32(N) tile, BK=16, 256 threads, 4x2 per thread.
// Grid: GEMM1 (32,8)=256 blocks (all CUs busy), GEMM2 (32,4)=128.
template <int KDIM>
__global__ __launch_bounds__(256) void k_gemm_bn_relu(const float* __restrict__ A,
                                                      const float* __restrict__ W,
                                                      const float* __restrict__ bias,
                                                      const float* __restrict__ gamma,
                                                      const float* __restrict__ beta,
                                                      float* __restrict__ out, int N) {
    constexpr int BK = 16;
    __shared__ float As[BK][64 + 4];  // As[k][m]
    __shared__ float Bs[BK][32 + 2];  // Bs[k][n]
    int tid = threadIdx.x;
    int tx = tid & 15;   // col group -> col0 = tx*2
    int ty = tid >> 4;   // row group -> row0 = ty*4
    int bm = blockIdx.x * 64, bn = blockIdx.y * 32;
    float c[4][2] = {};
    int lrow = tid >> 2;        // m in tile, 0..63
    int lcol = (tid & 3) * 4;   // k in tile {0,4,8,12}
    int brow = tid >> 4;        // k in tile for B, 0..15
    int bcol = (tid & 15) * 2;  // n in tile

    for (int k0 = 0; k0 < KDIM; k0 += BK) {
        float4 av = *(const float4*)(A + (size_t)(bm + lrow) * KDIM + k0 + lcol);
        float2 bv = *(const float2*)(W + (size_t)(k0 + brow) * N + bn + bcol);
        __syncthreads();
        As[lcol + 0][lrow] = av.x;
        As[lcol + 1][lrow] = av.y;
        As[lcol + 2][lrow] = av.z;
        As[lcol + 3][lrow] = av.w;
        Bs[brow][bcol] = bv.x;
        Bs[brow][bcol + 1] = bv.y;
        __syncthreads();
#pragma unroll
        for (int kk = 0; kk < BK; ++kk) {
            float4 a4 = *(const float4*)&As[kk][ty * 4];
            float2 b2 = *(const float2*)&Bs[kk][tx * 2];
            c[0][0] += a4.x * b2.x; c[0][1] += a4.x * b2.y;
            c[1][0] += a4.y * b2.x; c[1][1] += a4.y * b2.y;
            c[2][0] += a4.z * b2.x; c[2][1] += a4.z * b2.y;
            c[3][0] += a4.w * b2.x; c[3][1] += a4.w * b2.y;
        }
    }

    const float inv_bn = rsqrtf(1.0f + BN_EPS);
    int col0 = bn + tx * 2;
    float sc0 = gamma[col0] * inv_bn, sc1 = gamma[col0 + 1] * inv_bn;
    float bb0 = bias[col0], bb1 = bias[col0 + 1];
    float bt0 = beta[col0], bt1 = beta[col0 + 1];
#pragma unroll
    for (int i = 0; i < 4; ++i) {
        int row = bm + ty * 4 + i;
        float2 o;
        o.x = fmaxf((c[i][0] + bb0) * sc0 + bt0, 0.f);
        o.y = fmaxf((c[i][1] + bb1) * sc1 + bt1, 0.f);
        *(float2*)(out + (size_t)row * N + col0) = o;
    }
}

// ---------------- K7: logits + log-softmax + CE gather -----------------------
// W3 [128][126] staged in LDS; 8 rows per block; 128 threads (thread j = class j).
__global__ __launch_bounds__(128) void k_dann(const float* __restrict__ h2,
                                              const float* __restrict__ W3,
                                              const float* __restrict__ b3,
                                              const int* __restrict__ pid,
                                              const int* __restrict__ mapped,
                                              float* __restrict__ scal) {
    __shared__ float Ws[H2_][P_];  // 64512 B
    __shared__ float hrow[H2_];
    __shared__ float wmax[2], wsum[2], wfin[2];
    int t = threadIdx.x;
    for (int i = t; i < H2_ * P_; i += 128) Ws[i / P_][i % P_] = W3[i];
    int r0 = blockIdx.x * 8;
    float partial = 0.f;
    for (int r = 0; r < 8; ++r) {
        int b = r0 + r;
        __syncthreads();  // protect hrow/Ws (first iter) + wmax/wsum reuse
        hrow[t] = h2[(size_t)b * H2_ + t];
        __syncthreads();
        float logit = -INFINITY;
        if (t < P_) {
            float acc = b3[t];
#pragma unroll 8
            for (int k = 0; k < H2_; ++k) acc += hrow[k] * Ws[k][t];
            logit = acc;
        }
        float m = logit;
        for (int off = 32; off; off >>= 1) m = fmaxf(m, __shfl_down(m, off, 64));
        if ((t & 63) == 0) wmax[t >> 6] = m;
        __syncthreads();
        float M = fmaxf(wmax[0], wmax[1]);
        float e = (t < P_) ? __expf(logit - M) : 0.f;
        float se = e;
        for (int off = 32; off; off >>= 1) se += __shfl_down(se, off, 64);
        if ((t & 63) == 0) wsum[t >> 6] = se;
        __syncthreads();
        float SE = wsum[0] + wsum[1];
        int mb = mapped[pid[b]];
        if (t == mb) partial += (M + __logf(SE) - logit);
    }
    float s = partial;
    for (int off = 32; off; off >>= 1) s += __shfl_down(s, off, 64);
    if ((t & 63) == 0) wfin[t >> 6] = s;
    __syncthreads();
    if (t == 0) atomicAdd(&scal[2], wfin[0] + wfin[1]);
}

// ---------------- K8: combine --------------------------------------------------
__global__ void k_final(const float* __restrict__ scal, float* __restrict__ out) {
    float within = scal[0];
    float between = scal[1];
    float dann = scal[2];
    out[0] = L_PCSL * (within / (between + EPS)) + L_DANN * (dann / (float)B_);
}

extern "C" void kernel_launch(void* const* d_in, const int* in_sizes, int n_in,
                              void* d_out, int out_size, void* d_ws, size_t ws_size,
                              hipStream_t stream) {
    const float* feat = (const float*)d_in[0];
    const int* pid = (const int*)d_in[1];
    const float* W1 = (const float*)d_in[2];
    const float* b1 = (const float*)d_in[3];
    const float* g1 = (const float*)d_in[4];
    const float* be1 = (const float*)d_in[5];
    const float* W2 = (const float*)d_in[6];
    const float* b2 = (const float*)d_in[7];
    const float* g2 = (const float*)d_in[8];
    const float* be2 = (const float*)d_in[9];
    const float* W3 = (const float*)d_in[10];
    const float* b3 = (const float*)d_in[11];
    float* out = (float*)d_out;

    // Workspace layout (16B aligned chunks)
    char* w = (char*)d_ws;
    float* f = (float*)w;                              // B*D
    float* cent = f + (size_t)B_ * D_;                 // P*D
    float* h1 = cent + (size_t)P_ * D_;                // B*H1
    float* h2 = h1 + (size_t)B_ * H1_;                 // B*H2
    float* sq = h2 + (size_t)B_ * H2_;                 // 128 (P rounded)
    float* counts = sq + 128;                          // 128
    float* scal = counts + 128;                        // 16 scalars
    int* mapped = (int*)(scal + 16);                   // P ints

    // zero the atomic accumulators (scal[0]=within, [1]=between, [2]=dann)
    hipMemsetAsync(scal, 0, 16 * sizeof(float), stream);

    k_mean<<<B_, 192, 0, stream>>>(feat, f);
    k_centroid<<<P_, 192, 0, stream>>>(f, pid, cent, sq, counts);
    k_between<<<1, 256, 0, stream>>>(cent, sq, counts, scal, mapped);
    k_within<<<512, 256, 0, stream>>>(f, pid, cent, scal);
    k_gemm_bn_relu<D_><<<dim3(B_ / 64, H1_ / 32), 256, 0, stream>>>(f, W1, b1, g1, be1, h1, H1_);
    k_gemm_bn_relu<H1_><<<dim3(B_ / 64, H2_ / 32), 256, 0, stream>>>(h1, W2, b2, g2, be2, h2, H2_);
    k_dann<<<B_ / 8, 128, 0, stream>>>(h2, W3, b3, pid, mapped, scal);
    k_final<<<1, 1, 0, stream>>>(scal, out);
}

// Round 6
// 92.731 us; speedup vs baseline: 2.7700x; 1.6708x over previous
//
#include <hip/hip_runtime.h>
#include <math.h>

#define B_ 2048
#define S_ 16
#define D_ 768
#define H1_ 256
#define H2_ 128
#define P_ 126

static constexpr float EPS = 1e-6f;
static constexpr float BN_EPS = 1e-5f;
static constexpr float L_PCSL = 50.0f;
static constexpr float L_DANN = 0.5f;

typedef __attribute__((ext_vector_type(8))) short bf16x8;
typedef __attribute__((ext_vector_type(4))) float f32x4;

// fp32 -> bf16 round-to-nearest-even
__device__ inline unsigned short f2b(float x) {
    unsigned int u = __float_as_uint(x);
    unsigned int r = (u + 0x7fffu + ((u >> 16) & 1u)) >> 16;
    return (unsigned short)r;
}

// ---------------- K0: convert + transpose weights to bf16 --------------------
// dst[c][r] = bf16(src[r][c]); dst row-stride = R. Zero-pads cols >= C (W3: 126->128).
// 60 blocks of 64x64 tiles: W1 48, W2 8, W3 4.
__global__ __launch_bounds__(256) void k_cvt(const float* __restrict__ W1,
                                             const float* __restrict__ W2,
                                             const float* __restrict__ W3,
                                             unsigned short* __restrict__ W1T,
                                             unsigned short* __restrict__ W2T,
                                             unsigned short* __restrict__ W3T) {
    __shared__ float tile[64][65];
    int b = blockIdx.x;
    const float* src; unsigned short* dst; int R, C, r0, c0;
    if (b < 48)      { src = W1; dst = W1T; R = 768; C = 256; int t = b;      r0 = (t >> 2) * 64; c0 = (t & 3) * 64; }
    else if (b < 56) { src = W2; dst = W2T; R = 256; C = 128; int t = b - 48; r0 = (t >> 1) * 64; c0 = (t & 1) * 64; }
    else             { src = W3; dst = W3T; R = 128; C = 126; int t = b - 56; r0 = (t >> 1) * 64; c0 = (t & 1) * 64; }
    int tid = threadIdx.x;
#pragma unroll
    for (int i = 0; i < 16; ++i) {
        int idx = tid + i * 256;
        int rr = idx >> 6, cc = idx & 63;
        tile[rr][cc] = (c0 + cc < C) ? src[(size_t)(r0 + rr) * C + c0 + cc] : 0.f;
    }
    __syncthreads();
#pragma unroll
    for (int i = 0; i < 16; ++i) {
        int idx = tid + i * 256;
        int rr = idx >> 6, cc = idx & 63;
        dst[(size_t)(c0 + rr) * R + r0 + cc] = f2b(tile[cc][rr]);
    }
}

// ---------------- K1: f[b,d] = mean over s; emit f32 + bf16 ------------------
__global__ __launch_bounds__(192) void k_mean(const float* __restrict__ feat,
                                              float* __restrict__ f,
                                              unsigned short* __restrict__ fbf) {
    int b = blockIdx.x;
    int t = threadIdx.x;  // 0..191
    const float4* src = (const float4*)(feat + (size_t)b * S_ * D_);
    float4 acc = make_float4(0.f, 0.f, 0.f, 0.f);
#pragma unroll
    for (int s = 0; s < S_; ++s) {
        float4 v = src[s * (D_ / 4) + t];
        acc.x += v.x; acc.y += v.y; acc.z += v.z; acc.w += v.w;
    }
    const float inv = 1.0f / (float)S_;
    acc.x *= inv; acc.y *= inv; acc.z *= inv; acc.w *= inv;
    ((float4*)(f + (size_t)b * D_))[t] = acc;
    ((ushort4*)(fbf + (size_t)b * D_))[t] =
        make_ushort4(f2b(acc.x), f2b(acc.y), f2b(acc.z), f2b(acc.w));
}

// ---------------- K2: per-patient centroid via ballot match-list --------------
__global__ __launch_bounds__(192) void k_centroid(const float* __restrict__ f,
                                                  const int* __restrict__ pid,
                                                  float* __restrict__ cent,
                                                  float* __restrict__ sq,
                                                  float* __restrict__ counts) {
    __shared__ int sid[B_];
    __shared__ int list[B_];
    __shared__ int s_cnt;
    __shared__ float wred[3];
    int p = blockIdx.x;
    int t = threadIdx.x;
    for (int i = t; i < B_; i += 192) sid[i] = pid[i];
    __syncthreads();

    if (t < 64) {
        int total = 0;
        unsigned long long lt_mask = (t == 63) ? 0x7fffffffffffffffull
                                               : ((1ull << t) - 1ull);
#pragma unroll 4
        for (int r = 0; r < B_ / 64; ++r) {
            int b = r * 64 + t;
            bool m = (sid[b] == p);
            unsigned long long mask = __ballot(m);
            if (m) {
                int pos = total + (int)__popcll(mask & lt_mask);
                list[pos] = b;
            }
            total += (int)__popcll(mask);
        }
        if (t == 0) s_cnt = total;
    }
    __syncthreads();

    int cnt = s_cnt;
    float4 acc = make_float4(0.f, 0.f, 0.f, 0.f);
    int i = 0;
    for (; i + 4 <= cnt; i += 4) {
        int b0 = list[i], b1 = list[i + 1], b2 = list[i + 2], b3 = list[i + 3];
        float4 v0 = ((const float4*)(f + (size_t)b0 * D_))[t];
        float4 v1 = ((const float4*)(f + (size_t)b1 * D_))[t];
        float4 v2 = ((const float4*)(f + (size_t)b2 * D_))[t];
        float4 v3 = ((const float4*)(f + (size_t)b3 * D_))[t];
        acc.x += v0.x + v1.x + v2.x + v3.x;
        acc.y += v0.y + v1.y + v2.y + v3.y;
        acc.z += v0.z + v1.z + v2.z + v3.z;
        acc.w += v0.w + v1.w + v2.w + v3.w;
    }
    for (; i < cnt; ++i) {
        float4 v = ((const float4*)(f + (size_t)list[i] * D_))[t];
        acc.x += v.x; acc.y += v.y; acc.z += v.z; acc.w += v.w;
    }

    float invc = 1.0f / (float)(cnt > 0 ? cnt : 1);
    acc.x *= invc; acc.y *= invc; acc.z *= invc; acc.w *= invc;
    ((float4*)(cent + (size_t)p * D_))[t] = acc;
    float ss = acc.x * acc.x + acc.y * acc.y + acc.z * acc.z + acc.w * acc.w;
    for (int off = 32; off; off >>= 1) ss += __shfl_down(ss, off, 64);
    if ((t & 63) == 0) wred[t >> 6] = ss;
    __syncthreads();
    if (t == 0) {
        sq[p] = wred[0] + wred[1] + wred[2];
        counts[p] = (float)cnt;
    }
}

// ---------------- K3: within (blocks 0..511) + between/mapped (block 512) ----
__global__ __launch_bounds__(256) void k_wb(const float* __restrict__ f,
                                            const int* __restrict__ pid,
                                            const float* __restrict__ cent,
                                            const float* __restrict__ sq,
                                            const float* __restrict__ counts,
                                            float* __restrict__ scal,
                                            int* __restrict__ mapped) {
    __shared__ float wred[4];
    int t = threadIdx.x;
    if (blockIdx.x == 512) {
        // between = n_present * sum(sq) - ||sum_p centroid_p||^2
        float acc = 0.f;
        for (int d = t; d < D_; d += 256) {
            float cs = 0.f;
            for (int p = 0; p < P_; ++p) cs += cent[(size_t)p * D_ + d];
            acc += cs * cs;
        }
        for (int off = 32; off; off >>= 1) acc += __shfl_down(acc, off, 64);
        if ((t & 63) == 0) wred[t >> 6] = acc;
        __syncthreads();
        if (t == 0) {
            float B2 = wred[0] + wred[1] + wred[2] + wred[3];
            float ssq = 0.f;
            int run = 0;
            for (int p = 0; p < P_; ++p) {
                bool pres = counts[p] > 0.f;
                mapped[p] = pres ? run : -1;
                if (pres) { run++; ssq += sq[p]; }
            }
            scal[1] = (float)run * ssq - B2;
        }
        return;
    }
    const int total = B_ * D_ / 4;
    int idx = blockIdx.x * 256 + t;
    float accs = 0.f;
    for (int i = idx; i < total; i += 512 * 256) {
        int b = i / (D_ / 4);
        int dd = i % (D_ / 4);
        float4 fv = ((const float4*)f)[i];
        float4 cv = ((const float4*)(cent + (size_t)pid[b] * D_))[dd];
        float dx = fv.x - cv.x, dy = fv.y - cv.y, dz = fv.z - cv.z, dw = fv.w - cv.w;
        accs += dx * dx + dy * dy + dz * dz + dw * dw;
    }
    for (int off = 32; off; off >>= 1) accs += __shfl_down(accs, off, 64);
    if ((t & 63) == 0) wred[t >> 6] = accs;
    __syncthreads();
    if (t == 0) atomicAdd(&scal[0], wred[0] + wred[1] + wred[2] + wred[3]);
}

// ---------------- K4/K5: bf16 MFMA GEMM + bias + BN(eval) + ReLU -> bf16 -----
// C[M,N] = A[M,K] @ B[K,N], BT is [N][K] bf16. Tile 64(M) x 32(N), 4 waves.
// Per wave: 16 rows, 2 col-fragments, K/32 MFMA steps. No LDS, no barriers.
template <int K>
__global__ __launch_bounds__(256) void k_gemm_mfma(const unsigned short* __restrict__ A,
                                                   const unsigned short* __restrict__ BT,
                                                   const float* __restrict__ bias,
                                                   const float* __restrict__ gamma,
                                                   const float* __restrict__ beta,
                                                   unsigned short* __restrict__ out, int N) {
    int tid = threadIdx.x;
    int w = tid >> 6, lane = tid & 63, lg = lane >> 4, li = lane & 15;
    int bm = blockIdx.x * 64, bn = blockIdx.y * 32;
    const unsigned short* aptr = A + (size_t)(bm + w * 16 + li) * K + lg * 8;
    const unsigned short* bptr0 = BT + (size_t)(bn + li) * K + lg * 8;
    const unsigned short* bptr1 = BT + (size_t)(bn + 16 + li) * K + lg * 8;
    f32x4 acc0 = {0.f, 0.f, 0.f, 0.f};
    f32x4 acc1 = {0.f, 0.f, 0.f, 0.f};
#pragma unroll 4
    for (int k0 = 0; k0 < K; k0 += 32) {
        bf16x8 a8 = *(const bf16x8*)(aptr + k0);
        bf16x8 b80 = *(const bf16x8*)(bptr0 + k0);
        bf16x8 b81 = *(const bf16x8*)(bptr1 + k0);
        acc0 = __builtin_amdgcn_mfma_f32_16x16x32_bf16(a8, b80, acc0, 0, 0, 0);
        acc1 = __builtin_amdgcn_mfma_f32_16x16x32_bf16(a8, b81, acc1, 0, 0, 0);
    }
    const float inv_bn = rsqrtf(1.0f + BN_EPS);
    // C/D layout: col = lane&15, row = (lane>>4)*4 + reg  [m89/m91]
#pragma unroll
    for (int nf = 0; nf < 2; ++nf) {
        int col = bn + nf * 16 + li;
        float sc = gamma[col] * inv_bn;
        float bb = bias[col];
        float bt = beta[col];
        f32x4 a = nf ? acc1 : acc0;
#pragma unroll
        for (int r = 0; r < 4; ++r) {
            int row = bm + w * 16 + lg * 4 + r;
            float v = fmaxf((a[r] + bb) * sc + bt, 0.f);
            out[(size_t)row * N + col] = f2b(v);
        }
    }
}

// ---------------- K6: logits (MFMA) + log-softmax + CE -----------------------
// One wave per block, 16 rows. W3T is [128][128] bf16 (rows 126,127 zero).
__global__ __launch_bounds__(64) void k_dann(const unsigned short* __restrict__ h2bf,
                                             const unsigned short* __restrict__ W3T,
                                             const float* __restrict__ b3,
                                             const int* __restrict__ pid,
                                             const int* __restrict__ mapped,
                                             float* __restrict__ scal) {
    int lane = threadIdx.x;
    int lg = lane >> 4, li = lane & 15;
    int r0 = blockIdx.x * 16;
    f32x4 acc[8];
#pragma unroll
    for (int nf = 0; nf < 8; ++nf) acc[nf] = (f32x4){0.f, 0.f, 0.f, 0.f};
#pragma unroll
    for (int s = 0; s < 4; ++s) {
        bf16x8 a8 = *(const bf16x8*)(h2bf + (size_t)(r0 + li) * H2_ + s * 32 + lg * 8);
#pragma unroll
        for (int nf = 0; nf < 8; ++nf) {
            bf16x8 b8 = *(const bf16x8*)(W3T + (size_t)(nf * 16 + li) * H2_ + s * 32 + lg * 8);
            acc[nf] = __builtin_amdgcn_mfma_f32_16x16x32_bf16(a8, b8, acc[nf], 0, 0, 0);
        }
    }
    float b3v[8];
#pragma unroll
    for (int nf = 0; nf < 8; ++nf) {
        int col = nf * 16 + li;
        b3v[nf] = (col < P_) ? b3[col] : 0.f;
    }
    float partial = 0.f;
#pragma unroll
    for (int r = 0; r < 4; ++r) {
        int row = r0 + lg * 4 + r;  // all 16 li-lanes share this row, hold cols nf*16+li
        float lgt[8];
        float m = -INFINITY;
#pragma unroll
        for (int nf = 0; nf < 8; ++nf) {
            int col = nf * 16 + li;
            float v = (col < P_) ? (acc[nf][r] + b3v[nf]) : -INFINITY;
            lgt[nf] = v;
            m = fmaxf(m, v);
        }
        for (int off = 1; off < 16; off <<= 1) m = fmaxf(m, __shfl_xor(m, off, 64));
        float se = 0.f;
#pragma unroll
        for (int nf = 0; nf < 8; ++nf) se += __expf(lgt[nf] - m);  // exp(-inf)=0
        for (int off = 1; off < 16; off <<= 1) se += __shfl_xor(se, off, 64);
        int mb = mapped[pid[row]];
#pragma unroll
        for (int nf = 0; nf < 8; ++nf) {
            int col = nf * 16 + li;
            if (col == mb) partial += (m + __logf(se) - lgt[nf]);
        }
    }
    for (int off = 1; off < 64; off <<= 1) partial += __shfl_xor(partial, off, 64);
    if (lane == 0) atomicAdd(&scal[2], partial);
}

// ---------------- K7: combine -------------------------------------------------
__global__ void k_final(const float* __restrict__ scal, float* __restrict__ out) {
    float within = scal[0];
    float between = scal[1];
    float dann = scal[2];
    out[0] = L_PCSL * (within / (between + EPS)) + L_DANN * (dann / (float)B_);
}

extern "C" void kernel_launch(void* const* d_in, const int* in_sizes, int n_in,
                              void* d_out, int out_size, void* d_ws, size_t ws_size,
                              hipStream_t stream) {
    const float* feat = (const float*)d_in[0];
    const int* pid = (const int*)d_in[1];
    const float* W1 = (const float*)d_in[2];
    const float* b1 = (const float*)d_in[3];
    const float* g1 = (const float*)d_in[4];
    const float* be1 = (const float*)d_in[5];
    const float* W2 = (const float*)d_in[6];
    const float* b2 = (const float*)d_in[7];
    const float* g2 = (const float*)d_in[8];
    const float* be2 = (const float*)d_in[9];
    const float* W3 = (const float*)d_in[10];
    const float* b3 = (const float*)d_in[11];
    float* out = (float*)d_out;

    // Workspace layout
    char* w = (char*)d_ws;
    float* f = (float*)w;                                   // B*D f32
    float* cent = f + (size_t)B_ * D_;                      // P*D f32
    float* sq = cent + (size_t)P_ * D_;                     // 128
    float* counts = sq + 128;                               // 128
    float* scal = counts + 128;                             // 16
    int* mapped = (int*)(scal + 16);                        // 128
    unsigned short* fbf = (unsigned short*)(mapped + 128);  // B*D bf16
    unsigned short* h1bf = fbf + (size_t)B_ * D_;           // B*H1 bf16
    unsigned short* h2bf = h1bf + (size_t)B_ * H1_;         // B*H2 bf16
    unsigned short* W1T = h2bf + (size_t)B_ * H2_;          // H1*D bf16 [256][768]
    unsigned short* W2T = W1T + (size_t)H1_ * D_;           // H2*H1 bf16 [128][256]
    unsigned short* W3T = W2T + (size_t)H2_ * H1_;          // 128*128 bf16 (padded)

    hipMemsetAsync(scal, 0, 16 * sizeof(float), stream);

    k_cvt<<<60, 256, 0, stream>>>(W1, W2, W3, W1T, W2T, W3T);
    k_mean<<<B_, 192, 0, stream>>>(feat, f, fbf);
    k_centroid<<<P_, 192, 0, stream>>>(f, pid, cent, sq, counts);
    k_wb<<<513, 256, 0, stream>>>(f, pid, cent, sq, counts, scal, mapped);
    k_gemm_mfma<D_><<<dim3(B_ / 64, H1_ / 32), 256, 0, stream>>>(fbf, W1T, b1, g1, be1, h1bf, H1_);
    k_gemm_mfma<H1_><<<dim3(B_ / 64, H2_ / 32), 256, 0, stream>>>(h1bf, W2T, b2, g2, be2, h2bf, H2_);
    k_dann<<<B_ / 16, 64, 0, stream>>>(h2bf, W3T, b3, pid, mapped, scal);
    k_final<<<1, 1, 0, stream>>>(scal, out);
}

// Round 7
// 80.044 us; speedup vs baseline: 3.2091x; 1.1585x over previous
//
#include <hip/hip_runtime.h>
#include <math.h>

#define B_ 2048
#define S_ 16
#define D_ 768
#define H1_ 256
#define H2_ 128
#define P_ 126

static constexpr float EPS = 1e-6f;
static constexpr float BN_EPS = 1e-5f;
static constexpr float L_PCSL = 50.0f;
static constexpr float L_DANN = 0.5f;

typedef __attribute__((ext_vector_type(8))) short bf16x8;
typedef __attribute__((ext_vector_type(4))) float f32x4;

// fp32 -> bf16 round-to-nearest-even
__device__ inline unsigned short f2b(float x) {
    unsigned int u = __float_as_uint(x);
    unsigned int r = (u + 0x7fffu + ((u >> 16) & 1u)) >> 16;
    return (unsigned short)r;
}

// ---------------- K0: weights -> bf16 transposed (+ block 60: mapped ids) ----
// Blocks 0..59: 64x64 transpose tiles (W1 48, W2 8, W3 4; W3 zero-pads 126->128).
// Block 60: pid histogram -> mapped[p] = rank among present, -1 if absent.
__global__ __launch_bounds__(256) void k_cvt(const float* __restrict__ W1,
                                             const float* __restrict__ W2,
                                             const float* __restrict__ W3,
                                             unsigned short* __restrict__ W1T,
                                             unsigned short* __restrict__ W2T,
                                             unsigned short* __restrict__ W3T,
                                             const int* __restrict__ pid,
                                             int* __restrict__ mapped) {
    int b = blockIdx.x;
    int tid = threadIdx.x;
    if (b == 60) {
        __shared__ int hist[128];
        if (tid < 128) hist[tid] = 0;
        __syncthreads();
        for (int i = tid; i < B_; i += 256) atomicAdd(&hist[pid[i]], 1);
        __syncthreads();
        if (tid == 0) {
            int run = 0;
            for (int p = 0; p < P_; ++p) {
                mapped[p] = (hist[p] > 0) ? run : -1;
                if (hist[p] > 0) run++;
            }
        }
        return;
    }
    __shared__ float tile[64][65];
    const float* src; unsigned short* dst; int R, C, r0, c0;
    if (b < 48)      { src = W1; dst = W1T; R = 768; C = 256; int t = b;      r0 = (t >> 2) * 64; c0 = (t & 3) * 64; }
    else if (b < 56) { src = W2; dst = W2T; R = 256; C = 128; int t = b - 48; r0 = (t >> 1) * 64; c0 = (t & 1) * 64; }
    else             { src = W3; dst = W3T; R = 128; C = 126; int t = b - 56; r0 = (t >> 1) * 64; c0 = (t & 1) * 64; }
#pragma unroll
    for (int i = 0; i < 16; ++i) {
        int idx = tid + i * 256;
        int rr = idx >> 6, cc = idx & 63;
        tile[rr][cc] = (c0 + cc < C) ? src[(size_t)(r0 + rr) * C + c0 + cc] : 0.f;
    }
    __syncthreads();
#pragma unroll
    for (int i = 0; i < 16; ++i) {
        int idx = tid + i * 256;
        int rr = idx >> 6, cc = idx & 63;
        dst[(size_t)(c0 + rr) * R + r0 + cc] = f2b(tile[cc][rr]);
    }
}

// ---------------- K1: f[b,d] = mean over s; emit f32 + bf16 ------------------
__global__ __launch_bounds__(192) void k_mean(const float* __restrict__ feat,
                                              float* __restrict__ f,
                                              unsigned short* __restrict__ fbf) {
    int b = blockIdx.x;
    int t = threadIdx.x;  // 0..191
    const float4* src = (const float4*)(feat + (size_t)b * S_ * D_);
    float4 acc = make_float4(0.f, 0.f, 0.f, 0.f);
#pragma unroll
    for (int s = 0; s < S_; ++s) {
        float4 v = src[s * (D_ / 4) + t];
        acc.x += v.x; acc.y += v.y; acc.z += v.z; acc.w += v.w;
    }
    const float inv = 1.0f / (float)S_;
    acc.x *= inv; acc.y *= inv; acc.z *= inv; acc.w *= inv;
    ((float4*)(f + (size_t)b * D_))[t] = acc;
    ((ushort4*)(fbf + (size_t)b * D_))[t] =
        make_ushort4(f2b(acc.x), f2b(acc.y), f2b(acc.z), f2b(acc.w));
}

// ---------------- K2: per-patient centroid stats (ballot match-list) ---------
// Emits, via atomics: colsum[d] += c_p[d]; scal[3] += sum_rows ||f||^2;
// scal[4] += n_p*||c_p||^2; scal[5] += ||c_p||^2; scal[6] += present.
// within = scal[3]-scal[4]; between = scal[6]*scal[5]-||colsum||^2 (in k_final).
__global__ __launch_bounds__(192) void k_centroid(const float* __restrict__ f,
                                                  const int* __restrict__ pid,
                                                  float* __restrict__ colsum,
                                                  float* __restrict__ scal) {
    __shared__ int sid[B_];
    __shared__ int list[B_];
    __shared__ int s_cnt;
    __shared__ float wredA[3], wredB[3];
    int p = blockIdx.x;
    int t = threadIdx.x;
    for (int i = t; i < B_; i += 192) sid[i] = pid[i];
    __syncthreads();

    if (t < 64) {
        int total = 0;
        unsigned long long lt_mask = (t == 63) ? 0x7fffffffffffffffull
                                               : ((1ull << t) - 1ull);
#pragma unroll 4
        for (int r = 0; r < B_ / 64; ++r) {
            int b = r * 64 + t;
            bool m = (sid[b] == p);
            unsigned long long mask = __ballot(m);
            if (m) {
                int pos = total + (int)__popcll(mask & lt_mask);
                list[pos] = b;
            }
            total += (int)__popcll(mask);
        }
        if (t == 0) s_cnt = total;
    }
    __syncthreads();

    int cnt = s_cnt;
    float4 acc = make_float4(0.f, 0.f, 0.f, 0.f);
    float ssf = 0.f;  // sum of ||f_row||^2 over this patient's rows (this thread's 4 cols)
    int i = 0;
    for (; i + 4 <= cnt; i += 4) {
        int b0 = list[i], b1 = list[i + 1], b2 = list[i + 2], b3 = list[i + 3];
        float4 v0 = ((const float4*)(f + (size_t)b0 * D_))[t];
        float4 v1 = ((const float4*)(f + (size_t)b1 * D_))[t];
        float4 v2 = ((const float4*)(f + (size_t)b2 * D_))[t];
        float4 v3 = ((const float4*)(f + (size_t)b3 * D_))[t];
        acc.x += v0.x + v1.x + v2.x + v3.x;
        acc.y += v0.y + v1.y + v2.y + v3.y;
        acc.z += v0.z + v1.z + v2.z + v3.z;
        acc.w += v0.w + v1.w + v2.w + v3.w;
        ssf += v0.x * v0.x + v0.y * v0.y + v0.z * v0.z + v0.w * v0.w;
        ssf += v1.x * v1.x + v1.y * v1.y + v1.z * v1.z + v1.w * v1.w;
        ssf += v2.x * v2.x + v2.y * v2.y + v2.z * v2.z + v2.w * v2.w;
        ssf += v3.x * v3.x + v3.y * v3.y + v3.z * v3.z + v3.w * v3.w;
    }
    for (; i < cnt; ++i) {
        float4 v = ((const float4*)(f + (size_t)list[i] * D_))[t];
        acc.x += v.x; acc.y += v.y; acc.z += v.z; acc.w += v.w;
        ssf += v.x * v.x + v.y * v.y + v.z * v.z + v.w * v.w;
    }

    float invc = 1.0f / (float)(cnt > 0 ? cnt : 1);
    float4 c = make_float4(acc.x * invc, acc.y * invc, acc.z * invc, acc.w * invc);
    atomicAdd(&colsum[4 * t + 0], c.x);
    atomicAdd(&colsum[4 * t + 1], c.y);
    atomicAdd(&colsum[4 * t + 2], c.z);
    atomicAdd(&colsum[4 * t + 3], c.w);
    float ssc = c.x * c.x + c.y * c.y + c.z * c.z + c.w * c.w;
    for (int off = 32; off; off >>= 1) {
        ssf += __shfl_down(ssf, off, 64);
        ssc += __shfl_down(ssc, off, 64);
    }
    if ((t & 63) == 0) { wredA[t >> 6] = ssf; wredB[t >> 6] = ssc; }
    __syncthreads();
    if (t == 0) {
        float sumsq_rows = wredA[0] + wredA[1] + wredA[2];
        float sqp = wredB[0] + wredB[1] + wredB[2];
        atomicAdd(&scal[3], sumsq_rows);
        atomicAdd(&scal[4], (float)cnt * sqp);
        atomicAdd(&scal[5], sqp);
        atomicAdd(&scal[6], cnt > 0 ? 1.f : 0.f);
    }
}

// ---------------- K3: fused MLP: GEMM1+BN+ReLU -> GEMM2+BN+ReLU -> logits ----
// -> log-softmax -> CE.  128 blocks x 256 threads (4 waves), 16 rows per block.
// h1/h2 live only in LDS (padded strides => 2-way bank aliasing, free).
__global__ __launch_bounds__(256) void k_mlp(const unsigned short* __restrict__ fbf,
                                             const unsigned short* __restrict__ W1T,
                                             const unsigned short* __restrict__ W2T,
                                             const unsigned short* __restrict__ W3T,
                                             const float* __restrict__ b1,
                                             const float* __restrict__ g1,
                                             const float* __restrict__ be1,
                                             const float* __restrict__ b2,
                                             const float* __restrict__ g2,
                                             const float* __restrict__ be2,
                                             const float* __restrict__ b3,
                                             const int* __restrict__ pid,
                                             const int* __restrict__ mapped,
                                             float* __restrict__ scal) {
    constexpr int LD1 = H1_ + 8;  // 264 u16 = 528 B row stride
    constexpr int LD2 = H2_ + 8;  // 136 u16 = 272 B
    __shared__ unsigned short Hs[16 * LD1];
    __shared__ unsigned short H2s[16 * LD2];
    __shared__ float smax[4][16], ssum[4][16];
    __shared__ int spid[16];
    int tid = threadIdx.x;
    int w = tid >> 6, lane = tid & 63, lg = lane >> 4, li = lane & 15;
    int r0 = blockIdx.x * 16;
    if (tid < 16) spid[tid] = pid[r0 + tid];
    const float inv_bn = rsqrtf(1.0f + BN_EPS);

    // ---- GEMM1: h1[16][256], wave w owns cols w*64..w*64+63 (4 frags), K=768
    f32x4 acc[4];
#pragma unroll
    for (int nf = 0; nf < 4; ++nf) acc[nf] = (f32x4){0.f, 0.f, 0.f, 0.f};
    const unsigned short* aptr = fbf + (size_t)(r0 + li) * D_ + lg * 8;
#pragma unroll 2
    for (int k0 = 0; k0 < D_; k0 += 32) {
        bf16x8 a8 = *(const bf16x8*)(aptr + k0);
#pragma unroll
        for (int nf = 0; nf < 4; ++nf) {
            bf16x8 b8 = *(const bf16x8*)(W1T + (size_t)(w * 64 + nf * 16 + li) * D_ + k0 + lg * 8);
            acc[nf] = __builtin_amdgcn_mfma_f32_16x16x32_bf16(a8, b8, acc[nf], 0, 0, 0);
        }
    }
#pragma unroll
    for (int nf = 0; nf < 4; ++nf) {
        int col = w * 64 + nf * 16 + li;
        float sc = g1[col] * inv_bn, bb = b1[col], bt = be1[col];
#pragma unroll
        for (int r = 0; r < 4; ++r) {
            int row = lg * 4 + r;
            float v = fmaxf((acc[nf][r] + bb) * sc + bt, 0.f);
            Hs[row * LD1 + col] = f2b(v);
        }
    }
    __syncthreads();

    // ---- GEMM2: h2[16][128], wave w owns cols w*32..w*32+31 (2 frags), K=256
    f32x4 acc2[2];
    acc2[0] = (f32x4){0.f, 0.f, 0.f, 0.f};
    acc2[1] = (f32x4){0.f, 0.f, 0.f, 0.f};
#pragma unroll
    for (int ks = 0; ks < H1_ / 32; ++ks) {
        bf16x8 a8 = *(const bf16x8*)(Hs + li * LD1 + ks * 32 + lg * 8);
#pragma unroll
        for (int mf = 0; mf < 2; ++mf) {
            bf16x8 b8 = *(const bf16x8*)(W2T + (size_t)(w * 32 + mf * 16 + li) * H1_ + ks * 32 + lg * 8);
            acc2[mf] = __builtin_amdgcn_mfma_f32_16x16x32_bf16(a8, b8, acc2[mf], 0, 0, 0);
        }
    }
#pragma unroll
    for (int mf = 0; mf < 2; ++mf) {
        int col = w * 32 + mf * 16 + li;
        float sc = g2[col] * inv_bn, bb = b2[col], bt = be2[col];
#pragma unroll
        for (int r = 0; r < 4; ++r) {
            int row = lg * 4 + r;
            float v = fmaxf((acc2[mf][r] + bb) * sc + bt, 0.f);
            H2s[row * LD2 + col] = f2b(v);
        }
    }
    __syncthreads();

    // ---- logits[16][128]: wave w owns cols w*32..w*32+31, K=128
    f32x4 acc3[2];
    acc3[0] = (f32x4){0.f, 0.f, 0.f, 0.f};
    acc3[1] = (f32x4){0.f, 0.f, 0.f, 0.f};
#pragma unroll
    for (int ks = 0; ks < H2_ / 32; ++ks) {
        bf16x8 a8 = *(const bf16x8*)(H2s + li * LD2 + ks * 32 + lg * 8);
#pragma unroll
        for (int mf = 0; mf < 2; ++mf) {
            bf16x8 b8 = *(const bf16x8*)(W3T + (size_t)(w * 32 + mf * 16 + li) * H2_ + ks * 32 + lg * 8);
            acc3[mf] = __builtin_amdgcn_mfma_f32_16x16x32_bf16(a8, b8, acc3[mf], 0, 0, 0);
        }
    }
    int c0 = w * 32 + li, c1 = w * 32 + 16 + li;
    float bb0 = (c0 < P_) ? b3[c0] : 0.f;
    float bb1 = (c1 < P_) ? b3[c1] : 0.f;
    float lg0[4], lg1[4], m[4];
#pragma unroll
    for (int r = 0; r < 4; ++r) {
        lg0[r] = (c0 < P_) ? (acc3[0][r] + bb0) : -3.0e38f;
        lg1[r] = (c1 < P_) ? (acc3[1][r] + bb1) : -3.0e38f;
        m[r] = fmaxf(lg0[r], lg1[r]);
    }
    // reduce max over the 16 li-lanes (offsets 1..8 stay within the lg group)
#pragma unroll
    for (int off = 1; off < 16; off <<= 1)
#pragma unroll
        for (int r = 0; r < 4; ++r) m[r] = fmaxf(m[r], __shfl_xor(m[r], off, 64));
    if (li == 0) {
#pragma unroll
        for (int r = 0; r < 4; ++r) smax[w][lg * 4 + r] = m[r];
    }
    __syncthreads();
    float M[4], s[4];
#pragma unroll
    for (int r = 0; r < 4; ++r) {
        int row = lg * 4 + r;
        M[r] = fmaxf(fmaxf(smax[0][row], smax[1][row]), fmaxf(smax[2][row], smax[3][row]));
        s[r] = __expf(lg0[r] - M[r]) + __expf(lg1[r] - M[r]);
    }
#pragma unroll
    for (int off = 1; off < 16; off <<= 1)
#pragma unroll
        for (int r = 0; r < 4; ++r) s[r] += __shfl_xor(s[r], off, 64);
    if (li == 0) {
#pragma unroll
        for (int r = 0; r < 4; ++r) ssum[w][lg * 4 + r] = s[r];
    }
    __syncthreads();
    float part = 0.f;
#pragma unroll
    for (int r = 0; r < 4; ++r) {
        int row = lg * 4 + r;
        float se = ssum[0][row] + ssum[1][row] + ssum[2][row] + ssum[3][row];
        float lnse = M[r] + __logf(se);
        int mb = mapped[spid[row]];
        if (c0 == mb) part += lnse - lg0[r];
        if (c1 == mb) part += lnse - lg1[r];
    }
    for (int off = 32; off; off >>= 1) part += __shfl_down(part, off, 64);
    if (lane == 0) atomicAdd(&scal[2], part);
}

// ---------------- K4: finalize: between from colsum + combine ----------------
__global__ __launch_bounds__(256) void k_final(const float* __restrict__ colsum,
                                               const float* __restrict__ scal,
                                               float* __restrict__ out) {
    __shared__ float wred[4];
    int t = threadIdx.x;
    float acc = 0.f;
    for (int d = t; d < D_; d += 256) {
        float cs = colsum[d];
        acc += cs * cs;
    }
    for (int off = 32; off; off >>= 1) acc += __shfl_down(acc, off, 64);
    if ((t & 63) == 0) wred[t >> 6] = acc;
    __syncthreads();
    if (t == 0) {
        float B2 = wred[0] + wred[1] + wred[2] + wred[3];
        float within = scal[3] - scal[4];
        float between = scal[6] * scal[5] - B2;
        out[0] = L_PCSL * (within / (between + EPS)) + L_DANN * (scal[2] / (float)B_);
    }
}

extern "C" void kernel_launch(void* const* d_in, const int* in_sizes, int n_in,
                              void* d_out, int out_size, void* d_ws, size_t ws_size,
                              hipStream_t stream) {
    const float* feat = (const float*)d_in[0];
    const int* pid = (const int*)d_in[1];
    const float* W1 = (const float*)d_in[2];
    const float* b1 = (const float*)d_in[3];
    const float* g1 = (const float*)d_in[4];
    const float* be1 = (const float*)d_in[5];
    const float* W2 = (const float*)d_in[6];
    const float* b2 = (const float*)d_in[7];
    const float* g2 = (const float*)d_in[8];
    const float* be2 = (const float*)d_in[9];
    const float* W3 = (const float*)d_in[10];
    const float* b3 = (const float*)d_in[11];
    float* out = (float*)d_out;

    // Workspace layout (all 16B aligned)
    char* w = (char*)d_ws;
    float* colsum = (float*)w;                              // 768
    float* scal = colsum + D_;                              // 16
    int* mapped = (int*)(scal + 16);                        // 128
    float* f = (float*)(mapped + 128);                      // B*D f32
    unsigned short* fbf = (unsigned short*)(f + (size_t)B_ * D_);  // B*D bf16
    unsigned short* W1T = fbf + (size_t)B_ * D_;            // [256][768]
    unsigned short* W2T = W1T + (size_t)H1_ * D_;           // [128][256]
    unsigned short* W3T = W2T + (size_t)H2_ * H1_;          // [128][128] (padded)

    // zero colsum + scal accumulators
    hipMemsetAsync(colsum, 0, (D_ + 16) * sizeof(float), stream);

    k_cvt<<<61, 256, 0, stream>>>(W1, W2, W3, W1T, W2T, W3T, pid, mapped);
    k_mean<<<B_, 192, 0, stream>>>(feat, f, fbf);
    k_centroid<<<P_, 192, 0, stream>>>(f, pid, colsum, scal);
    k_mlp<<<B_ / 16, 256, 0, stream>>>(fbf, W1T, W2T, W3T, b1, g1, be1,
                                       b2, g2, be2, b3, pid, mapped, scal);
    k_final<<<1, 256, 0, stream>>>(colsum, scal, out);
}

// Round 8
// 76.055 us; speedup vs baseline: 3.3774x; 1.0525x over previous
//
#include <hip/hip_runtime.h>
#include <math.h>

#define B_ 2048
#define S_ 16
#define D_ 768
#define H1_ 256
#define H2_ 128
#define P_ 126

static constexpr float EPS = 1e-6f;
static constexpr float BN_EPS = 1e-5f;
static constexpr float L_PCSL = 50.0f;
static constexpr float L_DANN = 0.5f;

typedef __attribute__((ext_vector_type(8))) short bf16x8;
typedef __attribute__((ext_vector_type(4))) float f32x4;

// fp32 -> bf16 round-to-nearest-even
__device__ inline unsigned short f2b(float x) {
    unsigned int u = __float_as_uint(x);
    unsigned int r = (u + 0x7fffu + ((u >> 16) & 1u)) >> 16;
    return (unsigned short)r;
}
__device__ inline float b2f(unsigned short u) {
    return __uint_as_float((unsigned int)u << 16);
}
__device__ inline float4 ldrow(const unsigned short* __restrict__ fbf, int b, int t) {
    ushort4 u = ((const ushort4*)(fbf + (size_t)b * D_))[t];
    return make_float4(b2f(u.x), b2f(u.y), b2f(u.z), b2f(u.w));
}

// ---------------- K_pre: mean->bf16 (blocks 0..2047), weight cvt+transpose ----
// (blocks 2048..2107), pid histogram -> mapped (block 2108).
__global__ __launch_bounds__(256) void k_pre(const float* __restrict__ feat,
                                             unsigned short* __restrict__ fbf,
                                             const float* __restrict__ W1,
                                             const float* __restrict__ W2,
                                             const float* __restrict__ W3,
                                             unsigned short* __restrict__ W1T,
                                             unsigned short* __restrict__ W2T,
                                             unsigned short* __restrict__ W3T,
                                             const int* __restrict__ pid,
                                             int* __restrict__ mapped) {
    __shared__ union {
        float tile[64][65];
        int hist[128];
    } sh;
    int b = blockIdx.x;
    int tid = threadIdx.x;

    if (b < B_) {  // ---- mean over S=16 patches, emit bf16
        if (tid < 192) {
            const float4* src = (const float4*)(feat + (size_t)b * S_ * D_);
            float4 acc = make_float4(0.f, 0.f, 0.f, 0.f);
#pragma unroll
            for (int s = 0; s < S_; ++s) {
                float4 v = src[s * (D_ / 4) + tid];
                acc.x += v.x; acc.y += v.y; acc.z += v.z; acc.w += v.w;
            }
            const float inv = 1.0f / (float)S_;
            acc.x *= inv; acc.y *= inv; acc.z *= inv; acc.w *= inv;
            ((ushort4*)(fbf + (size_t)b * D_))[tid] =
                make_ushort4(f2b(acc.x), f2b(acc.y), f2b(acc.z), f2b(acc.w));
        }
        return;
    }
    if (b == B_ + 60) {  // ---- mapped-id table
        if (tid < 128) sh.hist[tid] = 0;
        __syncthreads();
        for (int i = tid; i < B_; i += 256) atomicAdd(&sh.hist[pid[i]], 1);
        __syncthreads();
        if (tid == 0) {
            int run = 0;
            for (int p = 0; p < P_; ++p) {
                mapped[p] = (sh.hist[p] > 0) ? run : -1;
                if (sh.hist[p] > 0) run++;
            }
        }
        return;
    }
    // ---- 64x64 transpose+cvt tile (W3 zero-pads cols 126->128)
    int bb = b - B_;
    const float* src; unsigned short* dst; int R, C, r0, c0;
    if (bb < 48)      { src = W1; dst = W1T; R = 768; C = 256; int t = bb;      r0 = (t >> 2) * 64; c0 = (t & 3) * 64; }
    else if (bb < 56) { src = W2; dst = W2T; R = 256; C = 128; int t = bb - 48; r0 = (t >> 1) * 64; c0 = (t & 1) * 64; }
    else              { src = W3; dst = W3T; R = 128; C = 126; int t = bb - 56; r0 = (t >> 1) * 64; c0 = (t & 1) * 64; }
#pragma unroll
    for (int i = 0; i < 16; ++i) {
        int idx = tid + i * 256;
        int rr = idx >> 6, cc = idx & 63;
        sh.tile[rr][cc] = (c0 + cc < C) ? src[(size_t)(r0 + rr) * C + c0 + cc] : 0.f;
    }
    __syncthreads();
#pragma unroll
    for (int i = 0; i < 16; ++i) {
        int idx = tid + i * 256;
        int rr = idx >> 6, cc = idx & 63;
        dst[(size_t)(c0 + rr) * R + r0 + cc] = f2b(sh.tile[cc][rr]);
    }
}

// ---------------- K_cm: centroid stats (blocks 0..125) || fused MLP+CE -------
// (blocks 126..253); last-finishing block computes between + final combine.
// within = scal[3]-scal[4]; between = scal[6]*scal[5]-||colsum||^2.
__global__ __launch_bounds__(256) void k_cm(const unsigned short* __restrict__ fbf,
                                            const int* __restrict__ pid,
                                            const unsigned short* __restrict__ W1T,
                                            const unsigned short* __restrict__ W2T,
                                            const unsigned short* __restrict__ W3T,
                                            const float* __restrict__ b1,
                                            const float* __restrict__ g1,
                                            const float* __restrict__ be1,
                                            const float* __restrict__ b2,
                                            const float* __restrict__ g2,
                                            const float* __restrict__ be2,
                                            const float* __restrict__ b3,
                                            const int* __restrict__ mapped,
                                            float* __restrict__ colsum,
                                            float* __restrict__ scal,
                                            float* __restrict__ out) {
    constexpr int LD1 = H1_ + 8;  // 264 u16
    constexpr int LD2 = H2_ + 8;  // 136 u16
    __shared__ union {
        struct { int sid[B_]; int list[B_]; } cen;
        struct {
            unsigned short Hs[16 * LD1];
            unsigned short H2s[16 * LD2];
            float smax[4][16], ssum[4][16];
            int spid[16];
        } mlp;
    } sh;
    __shared__ float wA[4], wB[4];
    __shared__ int s_cnt, amLast;
    int tid = threadIdx.x;
    int blk = blockIdx.x;
    int* ctr = (int*)(scal + 7);

    if (blk < P_) {
        // ================= centroid branch (patient p = blk) =================
        int p = blk;
        for (int i = tid; i < B_; i += 256) sh.cen.sid[i] = pid[i];
        __syncthreads();
        if (tid < 64) {
            int total = 0;
            unsigned long long lt_mask = (tid == 63) ? 0x7fffffffffffffffull
                                                     : ((1ull << tid) - 1ull);
#pragma unroll 4
            for (int r = 0; r < B_ / 64; ++r) {
                int b = r * 64 + tid;
                bool m = (sh.cen.sid[b] == p);
                unsigned long long mask = __ballot(m);
                if (m) {
                    int pos = total + (int)__popcll(mask & lt_mask);
                    sh.cen.list[pos] = b;
                }
                total += (int)__popcll(mask);
            }
            if (tid == 0) s_cnt = total;
        }
        __syncthreads();

        int cnt = s_cnt;
        float4 acc = make_float4(0.f, 0.f, 0.f, 0.f);
        float ssf = 0.f;
        if (tid < 192) {
            int i = 0;
            for (; i + 4 <= cnt; i += 4) {
                float4 v0 = ldrow(fbf, sh.cen.list[i], tid);
                float4 v1 = ldrow(fbf, sh.cen.list[i + 1], tid);
                float4 v2 = ldrow(fbf, sh.cen.list[i + 2], tid);
                float4 v3 = ldrow(fbf, sh.cen.list[i + 3], tid);
                acc.x += v0.x + v1.x + v2.x + v3.x;
                acc.y += v0.y + v1.y + v2.y + v3.y;
                acc.z += v0.z + v1.z + v2.z + v3.z;
                acc.w += v0.w + v1.w + v2.w + v3.w;
                ssf += v0.x * v0.x + v0.y * v0.y + v0.z * v0.z + v0.w * v0.w;
                ssf += v1.x * v1.x + v1.y * v1.y + v1.z * v1.z + v1.w * v1.w;
                ssf += v2.x * v2.x + v2.y * v2.y + v2.z * v2.z + v2.w * v2.w;
                ssf += v3.x * v3.x + v3.y * v3.y + v3.z * v3.z + v3.w * v3.w;
            }
            for (; i < cnt; ++i) {
                float4 v = ldrow(fbf, sh.cen.list[i], tid);
                acc.x += v.x; acc.y += v.y; acc.z += v.z; acc.w += v.w;
                ssf += v.x * v.x + v.y * v.y + v.z * v.z + v.w * v.w;
            }
        }
        float invc = 1.0f / (float)(cnt > 0 ? cnt : 1);
        float4 c = make_float4(acc.x * invc, acc.y * invc, acc.z * invc, acc.w * invc);
        if (tid < 192) {
            atomicAdd(&colsum[4 * tid + 0], c.x);
            atomicAdd(&colsum[4 * tid + 1], c.y);
            atomicAdd(&colsum[4 * tid + 2], c.z);
            atomicAdd(&colsum[4 * tid + 3], c.w);
        }
        float ssc = c.x * c.x + c.y * c.y + c.z * c.z + c.w * c.w;
        for (int off = 32; off; off >>= 1) {
            ssf += __shfl_down(ssf, off, 64);
            ssc += __shfl_down(ssc, off, 64);
        }
        if ((tid & 63) == 0) { wA[tid >> 6] = ssf; wB[tid >> 6] = ssc; }
        __syncthreads();
        if (tid == 0) {
            float sumsq_rows = wA[0] + wA[1] + wA[2] + wA[3];
            float sqp = wB[0] + wB[1] + wB[2] + wB[3];
            atomicAdd(&scal[3], sumsq_rows);
            atomicAdd(&scal[4], (float)cnt * sqp);
            atomicAdd(&scal[5], sqp);
            atomicAdd(&scal[6], cnt > 0 ? 1.f : 0.f);
        }
    } else {
        // ================= fused MLP branch (16 rows) ========================
        int w = tid >> 6, lane = tid & 63, lg = lane >> 4, li = lane & 15;
        int r0 = (blk - P_) * 16;
        if (tid < 16) sh.mlp.spid[tid] = pid[r0 + tid];
        const float inv_bn = rsqrtf(1.0f + BN_EPS);

        // GEMM1: h1[16][256], wave w owns cols w*64.., K=768
        f32x4 acc[4];
#pragma unroll
        for (int nf = 0; nf < 4; ++nf) acc[nf] = (f32x4){0.f, 0.f, 0.f, 0.f};
        const unsigned short* aptr = fbf + (size_t)(r0 + li) * D_ + lg * 8;
#pragma unroll 2
        for (int k0 = 0; k0 < D_; k0 += 32) {
            bf16x8 a8 = *(const bf16x8*)(aptr + k0);
#pragma unroll
            for (int nf = 0; nf < 4; ++nf) {
                bf16x8 b8 = *(const bf16x8*)(W1T + (size_t)(w * 64 + nf * 16 + li) * D_ + k0 + lg * 8);
                acc[nf] = __builtin_amdgcn_mfma_f32_16x16x32_bf16(a8, b8, acc[nf], 0, 0, 0);
            }
        }
#pragma unroll
        for (int nf = 0; nf < 4; ++nf) {
            int col = w * 64 + nf * 16 + li;
            float sc = g1[col] * inv_bn, bb = b1[col], bt = be1[col];
#pragma unroll
            for (int r = 0; r < 4; ++r) {
                int row = lg * 4 + r;
                float v = fmaxf((acc[nf][r] + bb) * sc + bt, 0.f);
                sh.mlp.Hs[row * LD1 + col] = f2b(v);
            }
        }
        __syncthreads();

        // GEMM2: h2[16][128], wave w owns cols w*32.., K=256
        f32x4 acc2[2];
        acc2[0] = (f32x4){0.f, 0.f, 0.f, 0.f};
        acc2[1] = (f32x4){0.f, 0.f, 0.f, 0.f};
#pragma unroll
        for (int ks = 0; ks < H1_ / 32; ++ks) {
            bf16x8 a8 = *(const bf16x8*)(sh.mlp.Hs + li * LD1 + ks * 32 + lg * 8);
#pragma unroll
            for (int mf = 0; mf < 2; ++mf) {
                bf16x8 b8 = *(const bf16x8*)(W2T + (size_t)(w * 32 + mf * 16 + li) * H1_ + ks * 32 + lg * 8);
                acc2[mf] = __builtin_amdgcn_mfma_f32_16x16x32_bf16(a8, b8, acc2[mf], 0, 0, 0);
            }
        }
#pragma unroll
        for (int mf = 0; mf < 2; ++mf) {
            int col = w * 32 + mf * 16 + li;
            float sc = g2[col] * inv_bn, bb = b2[col], bt = be2[col];
#pragma unroll
            for (int r = 0; r < 4; ++r) {
                int row = lg * 4 + r;
                float v = fmaxf((acc2[mf][r] + bb) * sc + bt, 0.f);
                sh.mlp.H2s[row * LD2 + col] = f2b(v);
            }
        }
        __syncthreads();

        // logits[16][128] + log-softmax + CE
        f32x4 acc3[2];
        acc3[0] = (f32x4){0.f, 0.f, 0.f, 0.f};
        acc3[1] = (f32x4){0.f, 0.f, 0.f, 0.f};
#pragma unroll
        for (int ks = 0; ks < H2_ / 32; ++ks) {
            bf16x8 a8 = *(const bf16x8*)(sh.mlp.H2s + li * LD2 + ks * 32 + lg * 8);
#pragma unroll
            for (int mf = 0; mf < 2; ++mf) {
                bf16x8 b8 = *(const bf16x8*)(W3T + (size_t)(w * 32 + mf * 16 + li) * H2_ + ks * 32 + lg * 8);
                acc3[mf] = __builtin_amdgcn_mfma_f32_16x16x32_bf16(a8, b8, acc3[mf], 0, 0, 0);
            }
        }
        int c0 = w * 32 + li, c1 = w * 32 + 16 + li;
        float bb0 = (c0 < P_) ? b3[c0] : 0.f;
        float bb1 = (c1 < P_) ? b3[c1] : 0.f;
        float lg0[4], lg1[4], m[4];
#pragma unroll
        for (int r = 0; r < 4; ++r) {
            lg0[r] = (c0 < P_) ? (acc3[0][r] + bb0) : -3.0e38f;
            lg1[r] = (c1 < P_) ? (acc3[1][r] + bb1) : -3.0e38f;
            m[r] = fmaxf(lg0[r], lg1[r]);
        }
#pragma unroll
        for (int off = 1; off < 16; off <<= 1)
#pragma unroll
            for (int r = 0; r < 4; ++r) m[r] = fmaxf(m[r], __shfl_xor(m[r], off, 64));
        if (li == 0) {
#pragma unroll
            for (int r = 0; r < 4; ++r) sh.mlp.smax[w][lg * 4 + r] = m[r];
        }
        __syncthreads();
        float M[4], s[4];
#pragma unroll
        for (int r = 0; r < 4; ++r) {
            int row = lg * 4 + r;
            M[r] = fmaxf(fmaxf(sh.mlp.smax[0][row], sh.mlp.smax[1][row]),
                         fmaxf(sh.mlp.smax[2][row], sh.mlp.smax[3][row]));
            s[r] = __expf(lg0[r] - M[r]) + __expf(lg1[r] - M[r]);
        }
#pragma unroll
        for (int off = 1; off < 16; off <<= 1)
#pragma unroll
            for (int r = 0; r < 4; ++r) s[r] += __shfl_xor(s[r], off, 64);
        if (li == 0) {
#pragma unroll
            for (int r = 0; r < 4; ++r) sh.mlp.ssum[w][lg * 4 + r] = s[r];
        }
        __syncthreads();
        float part = 0.f;
#pragma unroll
        for (int r = 0; r < 4; ++r) {
            int row = lg * 4 + r;
            float se = sh.mlp.ssum[0][row] + sh.mlp.ssum[1][row] +
                       sh.mlp.ssum[2][row] + sh.mlp.ssum[3][row];
            float lnse = M[r] + __logf(se);
            int mb = mapped[sh.mlp.spid[row]];
            if (c0 == mb) part += lnse - lg0[r];
            if (c1 == mb) part += lnse - lg1[r];
        }
        for (int off = 32; off; off >>= 1) part += __shfl_down(part, off, 64);
        if (lane == 0) atomicAdd(&scal[2], part);
    }

    // ================= last-block finalize ==================================
    __syncthreads();          // all this block's atomics drained (vmcnt before barrier)
    __threadfence();
    if (tid == 0) amLast = (atomicAdd(ctr, 1) == P_ + B_ / 16 - 1);
    __syncthreads();
    if (!amLast) return;
    // atomic readback -> coherent point (cross-XCD safe)
    float acc = 0.f;
    for (int d = tid; d < D_; d += 256) {
        float cs = atomicAdd(&colsum[d], 0.f);
        acc += cs * cs;
    }
    for (int off = 32; off; off >>= 1) acc += __shfl_down(acc, off, 64);
    if ((tid & 63) == 0) wA[tid >> 6] = acc;
    __syncthreads();
    if (tid == 0) {
        float B2 = wA[0] + wA[1] + wA[2] + wA[3];
        float within = atomicAdd(&scal[3], 0.f) - atomicAdd(&scal[4], 0.f);
        float between = atomicAdd(&scal[6], 0.f) * atomicAdd(&scal[5], 0.f) - B2;
        float dann = atomicAdd(&scal[2], 0.f);
        out[0] = L_PCSL * (within / (between + EPS)) + L_DANN * (dann / (float)B_);
    }
}

extern "C" void kernel_launch(void* const* d_in, const int* in_sizes, int n_in,
                              void* d_out, int out_size, void* d_ws, size_t ws_size,
                              hipStream_t stream) {
    const float* feat = (const float*)d_in[0];
    const int* pid = (const int*)d_in[1];
    const float* W1 = (const float*)d_in[2];
    const float* b1 = (const float*)d_in[3];
    const float* g1 = (const float*)d_in[4];
    const float* be1 = (const float*)d_in[5];
    const float* W2 = (const float*)d_in[6];
    const float* b2 = (const float*)d_in[7];
    const float* g2 = (const float*)d_in[8];
    const float* be2 = (const float*)d_in[9];
    const float* W3 = (const float*)d_in[10];
    const float* b3 = (const float*)d_in[11];
    float* out = (float*)d_out;

    // Workspace layout (16B aligned)
    char* w = (char*)d_ws;
    float* colsum = (float*)w;                              // 768
    float* scal = colsum + D_;                              // 16 (incl. counter at [7])
    int* mapped = (int*)(scal + 16);                        // 128
    unsigned short* fbf = (unsigned short*)(mapped + 128);  // B*D bf16
    unsigned short* W1T = fbf + (size_t)B_ * D_;            // [256][768]
    unsigned short* W2T = W1T + (size_t)H1_ * D_;           // [128][256]
    unsigned short* W3T = W2T + (size_t)H2_ * H1_;          // [128][128] (padded)

    // zero colsum + scal (incl. atomic accumulators and finalize counter)
    hipMemsetAsync(colsum, 0, (D_ + 16) * sizeof(float), stream);

    k_pre<<<B_ + 61, 256, 0, stream>>>(feat, fbf, W1, W2, W3, W1T, W2T, W3T, pid, mapped);
    k_cm<<<P_ + B_ / 16, 256, 0, stream>>>(fbf, pid, W1T, W2T, W3T,
                                           b1, g1, be1, b2, g2, be2, b3,
                                           mapped, colsum, scal, out);
}

// Round 9
// 71.948 us; speedup vs baseline: 3.5702x; 1.0571x over previous
//
#include <hip/hip_runtime.h>
#include <math.h>

#define B_ 2048
#define S_ 16
#define D_ 768
#define H1_ 256
#define H2_ 128
#define P_ 126

static constexpr float EPS = 1e-6f;
static constexpr float BN_EPS = 1e-5f;
static constexpr float L_PCSL = 50.0f;
static constexpr float L_DANN = 0.5f;

typedef __attribute__((ext_vector_type(8))) short bf16x8;
typedef __attribute__((ext_vector_type(4))) float f32x4;

// fp32 -> bf16 round-to-nearest-even
__device__ inline unsigned short f2b(float x) {
    unsigned int u = __float_as_uint(x);
    unsigned int r = (u + 0x7fffu + ((u >> 16) & 1u)) >> 16;
    return (unsigned short)r;
}
__device__ inline float b2f(unsigned short u) {
    return __uint_as_float((unsigned int)u << 16);
}
__device__ inline float4 ldrow(const unsigned short* __restrict__ fbf, int b, int t) {
    ushort4 u = ((const ushort4*)(fbf + (size_t)b * D_))[t];
    return make_float4(b2f(u.x), b2f(u.y), b2f(u.z), b2f(u.w));
}

// ---------------- K_pre: mean->bf16 (blocks 0..2047), weight cvt+transpose ----
// (blocks 2048..2107), pid histogram -> mapped + ZERO accumulators (block 2108).
// No hipMemsetAsync in the graph: the 3 KB fill node cost ~57 us/replay (SDMA
// cross-queue sync), so the zeroing lives here instead.
__global__ __launch_bounds__(256) void k_pre(const float* __restrict__ feat,
                                             unsigned short* __restrict__ fbf,
                                             const float* __restrict__ W1,
                                             const float* __restrict__ W2,
                                             const float* __restrict__ W3,
                                             unsigned short* __restrict__ W1T,
                                             unsigned short* __restrict__ W2T,
                                             unsigned short* __restrict__ W3T,
                                             const int* __restrict__ pid,
                                             int* __restrict__ mapped,
                                             float* __restrict__ colsum,
                                             float* __restrict__ scal) {
    __shared__ union {
        float tile[64][65];
        int hist[128];
    } sh;
    int b = blockIdx.x;
    int tid = threadIdx.x;

    if (b < B_) {  // ---- mean over S=16 patches, emit bf16
        if (tid < 192) {
            const float4* src = (const float4*)(feat + (size_t)b * S_ * D_);
            float4 acc = make_float4(0.f, 0.f, 0.f, 0.f);
#pragma unroll
            for (int s = 0; s < S_; ++s) {
                float4 v = src[s * (D_ / 4) + tid];
                acc.x += v.x; acc.y += v.y; acc.z += v.z; acc.w += v.w;
            }
            const float inv = 1.0f / (float)S_;
            acc.x *= inv; acc.y *= inv; acc.z *= inv; acc.w *= inv;
            ((ushort4*)(fbf + (size_t)b * D_))[tid] =
                make_ushort4(f2b(acc.x), f2b(acc.y), f2b(acc.z), f2b(acc.w));
        }
        return;
    }
    if (b == B_ + 60) {  // ---- zero accumulators + mapped-id table
        if (tid < 192) ((float4*)colsum)[tid] = make_float4(0.f, 0.f, 0.f, 0.f);
        if (tid >= 192 && tid < 208) scal[tid - 192] = 0.f;  // incl. finalize ctr
        if (tid < 128) sh.hist[tid] = 0;
        __syncthreads();
        for (int i = tid; i < B_; i += 256) atomicAdd(&sh.hist[pid[i]], 1);
        __syncthreads();
        if (tid == 0) {
            int run = 0;
            for (int p = 0; p < P_; ++p) {
                mapped[p] = (sh.hist[p] > 0) ? run : -1;
                if (sh.hist[p] > 0) run++;
            }
        }
        return;
    }
    // ---- 64x64 transpose+cvt tile (W3 zero-pads cols 126->128)
    int bb = b - B_;
    const float* src; unsigned short* dst; int R, C, r0, c0;
    if (bb < 48)      { src = W1; dst = W1T; R = 768; C = 256; int t = bb;      r0 = (t >> 2) * 64; c0 = (t & 3) * 64; }
    else if (bb < 56) { src = W2; dst = W2T; R = 256; C = 128; int t = bb - 48; r0 = (t >> 1) * 64; c0 = (t & 1) * 64; }
    else              { src = W3; dst = W3T; R = 128; C = 126; int t = bb - 56; r0 = (t >> 1) * 64; c0 = (t & 1) * 64; }
#pragma unroll
    for (int i = 0; i < 16; ++i) {
        int idx = tid + i * 256;
        int rr = idx >> 6, cc = idx & 63;
        sh.tile[rr][cc] = (c0 + cc < C) ? src[(size_t)(r0 + rr) * C + c0 + cc] : 0.f;
    }
    __syncthreads();
#pragma unroll
    for (int i = 0; i < 16; ++i) {
        int idx = tid + i * 256;
        int rr = idx >> 6, cc = idx & 63;
        dst[(size_t)(c0 + rr) * R + r0 + cc] = f2b(sh.tile[cc][rr]);
    }
}

// ---------------- K_cm: centroid stats (blocks 0..125) || fused MLP+CE -------
// (blocks 126..253); last-finishing block computes between + final combine.
// within = scal[3]-scal[4]; between = scal[6]*scal[5]-||colsum||^2.
__global__ __launch_bounds__(256) void k_cm(const unsigned short* __restrict__ fbf,
                                            const int* __restrict__ pid,
                                            const unsigned short* __restrict__ W1T,
                                            const unsigned short* __restrict__ W2T,
                                            const unsigned short* __restrict__ W3T,
                                            const float* __restrict__ b1,
                                            const float* __restrict__ g1,
                                            const float* __restrict__ be1,
                                            const float* __restrict__ b2,
                                            const float* __restrict__ g2,
                                            const float* __restrict__ be2,
                                            const float* __restrict__ b3,
                                            const int* __restrict__ mapped,
                                            float* __restrict__ colsum,
                                            float* __restrict__ scal,
                                            float* __restrict__ out) {
    constexpr int LD1 = H1_ + 8;  // 264 u16
    constexpr int LD2 = H2_ + 8;  // 136 u16
    __shared__ union {
        struct { int sid[B_]; int list[B_]; } cen;
        struct {
            unsigned short Hs[16 * LD1];
            unsigned short H2s[16 * LD2];
            float smax[4][16], ssum[4][16];
            int spid[16];
        } mlp;
    } sh;
    __shared__ float wA[4], wB[4];
    __shared__ int s_cnt, amLast;
    int tid = threadIdx.x;
    int blk = blockIdx.x;
    int* ctr = (int*)(scal + 7);

    if (blk < P_) {
        // ================= centroid branch (patient p = blk) =================
        int p = blk;
        for (int i = tid; i < B_; i += 256) sh.cen.sid[i] = pid[i];
        __syncthreads();
        if (tid < 64) {
            int total = 0;
            unsigned long long lt_mask = (tid == 63) ? 0x7fffffffffffffffull
                                                     : ((1ull << tid) - 1ull);
#pragma unroll 4
            for (int r = 0; r < B_ / 64; ++r) {
                int b = r * 64 + tid;
                bool m = (sh.cen.sid[b] == p);
                unsigned long long mask = __ballot(m);
                if (m) {
                    int pos = total + (int)__popcll(mask & lt_mask);
                    sh.cen.list[pos] = b;
                }
                total += (int)__popcll(mask);
            }
            if (tid == 0) s_cnt = total;
        }
        __syncthreads();

        int cnt = s_cnt;
        float4 acc = make_float4(0.f, 0.f, 0.f, 0.f);
        float ssf = 0.f;
        if (tid < 192) {
            int i = 0;
            for (; i + 4 <= cnt; i += 4) {
                float4 v0 = ldrow(fbf, sh.cen.list[i], tid);
                float4 v1 = ldrow(fbf, sh.cen.list[i + 1], tid);
                float4 v2 = ldrow(fbf, sh.cen.list[i + 2], tid);
                float4 v3 = ldrow(fbf, sh.cen.list[i + 3], tid);
                acc.x += v0.x + v1.x + v2.x + v3.x;
                acc.y += v0.y + v1.y + v2.y + v3.y;
                acc.z += v0.z + v1.z + v2.z + v3.z;
                acc.w += v0.w + v1.w + v2.w + v3.w;
                ssf += v0.x * v0.x + v0.y * v0.y + v0.z * v0.z + v0.w * v0.w;
                ssf += v1.x * v1.x + v1.y * v1.y + v1.z * v1.z + v1.w * v1.w;
                ssf += v2.x * v2.x + v2.y * v2.y + v2.z * v2.z + v2.w * v2.w;
                ssf += v3.x * v3.x + v3.y * v3.y + v3.z * v3.z + v3.w * v3.w;
            }
            for (; i < cnt; ++i) {
                float4 v = ldrow(fbf, sh.cen.list[i], tid);
                acc.x += v.x; acc.y += v.y; acc.z += v.z; acc.w += v.w;
                ssf += v.x * v.x + v.y * v.y + v.z * v.z + v.w * v.w;
            }
        }
        float invc = 1.0f / (float)(cnt > 0 ? cnt : 1);
        float4 c = make_float4(acc.x * invc, acc.y * invc, acc.z * invc, acc.w * invc);
        if (tid < 192) {
            atomicAdd(&colsum[4 * tid + 0], c.x);
            atomicAdd(&colsum[4 * tid + 1], c.y);
            atomicAdd(&colsum[4 * tid + 2], c.z);
            atomicAdd(&colsum[4 * tid + 3], c.w);
        }
        float ssc = c.x * c.x + c.y * c.y + c.z * c.z + c.w * c.w;
        for (int off = 32; off; off >>= 1) {
            ssf += __shfl_down(ssf, off, 64);
            ssc += __shfl_down(ssc, off, 64);
        }
        if ((tid & 63) == 0) { wA[tid >> 6] = ssf; wB[tid >> 6] = ssc; }
        __syncthreads();
        if (tid == 0) {
            float sumsq_rows = wA[0] + wA[1] + wA[2] + wA[3];
            float sqp = wB[0] + wB[1] + wB[2] + wB[3];
            atomicAdd(&scal[3], sumsq_rows);
            atomicAdd(&scal[4], (float)cnt * sqp);
            atomicAdd(&scal[5], sqp);
            atomicAdd(&scal[6], cnt > 0 ? 1.f : 0.f);
        }
    } else {
        // ================= fused MLP branch (16 rows) ========================
        int w = tid >> 6, lane = tid & 63, lg = lane >> 4, li = lane & 15;
        int r0 = (blk - P_) * 16;
        if (tid < 16) sh.mlp.spid[tid] = pid[r0 + tid];
        const float inv_bn = rsqrtf(1.0f + BN_EPS);

        // GEMM1: h1[16][256], wave w owns cols w*64.., K=768
        f32x4 acc[4];
#pragma unroll
        for (int nf = 0; nf < 4; ++nf) acc[nf] = (f32x4){0.f, 0.f, 0.f, 0.f};
        const unsigned short* aptr = fbf + (size_t)(r0 + li) * D_ + lg * 8;
#pragma unroll 2
        for (int k0 = 0; k0 < D_; k0 += 32) {
            bf16x8 a8 = *(const bf16x8*)(aptr + k0);
#pragma unroll
            for (int nf = 0; nf < 4; ++nf) {
                bf16x8 b8 = *(const bf16x8*)(W1T + (size_t)(w * 64 + nf * 16 + li) * D_ + k0 + lg * 8);
                acc[nf] = __builtin_amdgcn_mfma_f32_16x16x32_bf16(a8, b8, acc[nf], 0, 0, 0);
            }
        }
#pragma unroll
        for (int nf = 0; nf < 4; ++nf) {
            int col = w * 64 + nf * 16 + li;
            float sc = g1[col] * inv_bn, bb = b1[col], bt = be1[col];
#pragma unroll
            for (int r = 0; r < 4; ++r) {
                int row = lg * 4 + r;
                float v = fmaxf((acc[nf][r] + bb) * sc + bt, 0.f);
                sh.mlp.Hs[row * LD1 + col] = f2b(v);
            }
        }
        __syncthreads();

        // GEMM2: h2[16][128], wave w owns cols w*32.., K=256
        f32x4 acc2[2];
        acc2[0] = (f32x4){0.f, 0.f, 0.f, 0.f};
        acc2[1] = (f32x4){0.f, 0.f, 0.f, 0.f};
#pragma unroll
        for (int ks = 0; ks < H1_ / 32; ++ks) {
            bf16x8 a8 = *(const bf16x8*)(sh.mlp.Hs + li * LD1 + ks * 32 + lg * 8);
#pragma unroll
            for (int mf = 0; mf < 2; ++mf) {
                bf16x8 b8 = *(const bf16x8*)(W2T + (size_t)(w * 32 + mf * 16 + li) * H1_ + ks * 32 + lg * 8);
                acc2[mf] = __builtin_amdgcn_mfma_f32_16x16x32_bf16(a8, b8, acc2[mf], 0, 0, 0);
            }
        }
#pragma unroll
        for (int mf = 0; mf < 2; ++mf) {
            int col = w * 32 + mf * 16 + li;
            float sc = g2[col] * inv_bn, bb = b2[col], bt = be2[col];
#pragma unroll
            for (int r = 0; r < 4; ++r) {
                int row = lg * 4 + r;
                float v = fmaxf((acc2[mf][r] + bb) * sc + bt, 0.f);
                sh.mlp.H2s[row * LD2 + col] = f2b(v);
            }
        }
        __syncthreads();

        // logits[16][128] + log-softmax + CE
        f32x4 acc3[2];
        acc3[0] = (f32x4){0.f, 0.f, 0.f, 0.f};
        acc3[1] = (f32x4){0.f, 0.f, 0.f, 0.f};
#pragma unroll
        for (int ks = 0; ks < H2_ / 32; ++ks) {
            bf16x8 a8 = *(const bf16x8*)(sh.mlp.H2s + li * LD2 + ks * 32 + lg * 8);
#pragma unroll
            for (int mf = 0; mf < 2; ++mf) {
                bf16x8 b8 = *(const bf16x8*)(W3T + (size_t)(w * 32 + mf * 16 + li) * H2_ + ks * 32 + lg * 8);
                acc3[mf] = __builtin_amdgcn_mfma_f32_16x16x32_bf16(a8, b8, acc3[mf], 0, 0, 0);
            }
        }
        int c0 = w * 32 + li, c1 = w * 32 + 16 + li;
        float bb0 = (c0 < P_) ? b3[c0] : 0.f;
        float bb1 = (c1 < P_) ? b3[c1] : 0.f;
        float lg0[4], lg1[4], m[4];
#pragma unroll
        for (int r = 0; r < 4; ++r) {
            lg0[r] = (c0 < P_) ? (acc3[0][r] + bb0) : -3.0e38f;
            lg1[r] = (c1 < P_) ? (acc3[1][r] + bb1) : -3.0e38f;
            m[r] = fmaxf(lg0[r], lg1[r]);
        }
#pragma unroll
        for (int off = 1; off < 16; off <<= 1)
#pragma unroll
            for (int r = 0; r < 4; ++r) m[r] = fmaxf(m[r], __shfl_xor(m[r], off, 64));
        if (li == 0) {
#pragma unroll
            for (int r = 0; r < 4; ++r) sh.mlp.smax[w][lg * 4 + r] = m[r];
        }
        __syncthreads();
        float M[4], s[4];
#pragma unroll
        for (int r = 0; r < 4; ++r) {
            int row = lg * 4 + r;
            M[r] = fmaxf(fmaxf(sh.mlp.smax[0][row], sh.mlp.smax[1][row]),
                         fmaxf(sh.mlp.smax[2][row], sh.mlp.smax[3][row]));
            s[r] = __expf(lg0[r] - M[r]) + __expf(lg1[r] - M[r]);
        }
#pragma unroll
        for (int off = 1; off < 16; off <<= 1)
#pragma unroll
            for (int r = 0; r < 4; ++r) s[r] += __shfl_xor(s[r], off, 64);
        if (li == 0) {
#pragma unroll
            for (int r = 0; r < 4; ++r) sh.mlp.ssum[w][lg * 4 + r] = s[r];
        }
        __syncthreads();
        float part = 0.f;
#pragma unroll
        for (int r = 0; r < 4; ++r) {
            int row = lg * 4 + r;
            float se = sh.mlp.ssum[0][row] + sh.mlp.ssum[1][row] +
                       sh.mlp.ssum[2][row] + sh.mlp.ssum[3][row];
            float lnse = M[r] + __logf(se);
            int mb = mapped[sh.mlp.spid[row]];
            if (c0 == mb) part += lnse - lg0[r];
            if (c1 == mb) part += lnse - lg1[r];
        }
        for (int off = 32; off; off >>= 1) part += __shfl_down(part, off, 64);
        if (lane == 0) atomicAdd(&scal[2], part);
    }

    // ================= last-block finalize ==================================
    __syncthreads();          // all this block's atomics drained (vmcnt before barrier)
    __threadfence();
    if (tid == 0) amLast = (atomicAdd(ctr, 1) == P_ + B_ / 16 - 1);
    __syncthreads();
    if (!amLast) return;
    // atomic readback -> coherent point (cross-XCD safe)
    float acc = 0.f;
    for (int d = tid; d < D_; d += 256) {
        float cs = atomicAdd(&colsum[d], 0.f);
        acc += cs * cs;
    }
    for (int off = 32; off; off >>= 1) acc += __shfl_down(acc, off, 64);
    if ((tid & 63) == 0) wA[tid >> 6] = acc;
    __syncthreads();
    if (tid == 0) {
        float B2 = wA[0] + wA[1] + wA[2] + wA[3];
        float within = atomicAdd(&scal[3], 0.f) - atomicAdd(&scal[4], 0.f);
        float between = atomicAdd(&scal[6], 0.f) * atomicAdd(&scal[5], 0.f) - B2;
        float dann = atomicAdd(&scal[2], 0.f);
        out[0] = L_PCSL * (within / (between + EPS)) + L_DANN * (dann / (float)B_);
    }
}

extern "C" void kernel_launch(void* const* d_in, const int* in_sizes, int n_in,
                              void* d_out, int out_size, void* d_ws, size_t ws_size,
                              hipStream_t stream) {
    const float* feat = (const float*)d_in[0];
    const int* pid = (const int*)d_in[1];
    const float* W1 = (const float*)d_in[2];
    const float* b1 = (const float*)d_in[3];
    const float* g1 = (const float*)d_in[4];
    const float* be1 = (const float*)d_in[5];
    const float* W2 = (const float*)d_in[6];
    const float* b2 = (const float*)d_in[7];
    const float* g2 = (const float*)d_in[8];
    const float* be2 = (const float*)d_in[9];
    const float* W3 = (const float*)d_in[10];
    const float* b3 = (const float*)d_in[11];
    float* out = (float*)d_out;

    // Workspace layout (16B aligned)
    char* w = (char*)d_ws;
    float* colsum = (float*)w;                              // 768
    float* scal = colsum + D_;                              // 16 (incl. counter at [7])
    int* mapped = (int*)(scal + 16);                        // 128
    unsigned short* fbf = (unsigned short*)(mapped + 128);  // B*D bf16
    unsigned short* W1T = fbf + (size_t)B_ * D_;            // [256][768]
    unsigned short* W2T = W1T + (size_t)H1_ * D_;           // [128][256]
    unsigned short* W3T = W2T + (size_t)H2_ * H1_;          // [128][128] (padded)

    // NOTE: no hipMemsetAsync — the fill node cost ~57 us/replay (cross-engine
    // sync in graph replay). k_pre block B_+60 zeroes colsum/scal instead.
    k_pre<<<B_ + 61, 256, 0, stream>>>(feat, fbf, W1, W2, W3, W1T, W2T, W3T,
                                       pid, mapped, colsum, scal);
    k_cm<<<P_ + B_ / 16, 256, 0, stream>>>(fbf, pid, W1T, W2T, W3T,
                                           b1, g1, be1, b2, g2, be2, b3,
                                           mapped, colsum, scal, out);
}